// Round 8
// baseline (184.371 us; speedup 1.0000x reference)
//
#include <hip/hip_runtime.h>
#include <hip/hip_bf16.h>

#define B_ 8
#define S_ 1024
#define U_ 1024
#define H_ 16
#define DK_ 64

typedef __attribute__((ext_vector_type(8))) short short8;
typedef __attribute__((ext_vector_type(4))) float f32x4;
typedef __attribute__((ext_vector_type(16))) float f32x16;

__device__ inline ushort f2b(float x) {
  union { float f; unsigned u; } v; v.f = x;
  unsigned r = (v.u + 0x7FFFu + ((v.u >> 16) & 1u)) >> 16;
  return (ushort)r;
}
__device__ inline unsigned pk2(float lo, float hi) {
  return (unsigned)f2b(lo) | ((unsigned)f2b(hi) << 16);
}

__device__ inline void gld16(const ushort* g, ushort* l) {
  __builtin_amdgcn_global_load_lds((__attribute__((address_space(1))) void*)(g),
                                   (__attribute__((address_space(3))) void*)(l),
                                   16, 0, 0);
}

// ---------------- pack query fp32 -> bf16 ----------------
__global__ __launch_bounds__(256) void pack_x_kern(const float* __restrict__ X,
                                                   ushort* __restrict__ Xb) {
  int idx = blockIdx.x * 256 + threadIdx.x;
  const float4* src = (const float4*)X + (size_t)idx * 2;
  float4 a = src[0], b = src[1];
  ushort r[8];
  r[0]=f2b(a.x); r[1]=f2b(a.y); r[2]=f2b(a.z); r[3]=f2b(a.w);
  r[4]=f2b(b.x); r[5]=f2b(b.y); r[6]=f2b(b.z); r[7]=f2b(b.w);
  *(uint4*)(Xb + (size_t)idx*8) = *(uint4*)r;
}

// ---------------- pack weights (transpose to [n][k], bf16) ----------------
__global__ __launch_bounds__(256) void pack_w_kern(
    const float* __restrict__ Wq, const float* __restrict__ Wk, const float* __restrict__ Wv,
    const float* __restrict__ bq, const float* __restrict__ bk, const float* __restrict__ bv,
    const float* __restrict__ Wo,
    ushort* __restrict__ Wqkv, float* __restrict__ Bqkv, ushort* __restrict__ Wob)
{
  __shared__ ushort tile[64*65];
  const int t = threadIdx.x;
  const int bid = blockIdx.x;
  if (bid < 768) {
    int p = bid >> 8, rem = bid & 255;
    int h = rem >> 4, kc = rem & 15, k0 = kc*64;
    const float* Wsrc = (p==0) ? Wq : ((p==1) ? Wk : Wv);
    #pragma unroll
    for (int i = 0; i < 16; ++i) {
      int e = t + i*256;
      int r = e >> 6, d = e & 63;
      tile[d*65 + r] = f2b(Wsrc[h*65536 + (k0+r)*64 + d]);
    }
    __syncthreads();
    #pragma unroll
    for (int i = 0; i < 16; ++i) {
      int e = t + i*256;
      int d = e >> 6, r = e & 63;
      Wqkv[(size_t)(p*1024 + h*64 + d)*1024 + k0 + r] = tile[d*65 + r];
    }
    if (kc == 0 && t < 64) {
      const float* bsrc = (p==0) ? bq : ((p==1) ? bk : bv);
      Bqkv[p*1024 + h*64 + t] = bsrc[h*64 + t];
    }
  } else {
    int b2 = bid - 768;
    int nc = b2 >> 4, kc = b2 & 15;
    int n0 = nc*64, k0 = kc*64;
    #pragma unroll
    for (int i = 0; i < 16; ++i) {
      int e = t + i*256;
      int r = e >> 6, d = e & 63;
      tile[d*65 + r] = f2b(Wo[(size_t)(k0+r)*1024 + n0 + d]);
    }
    __syncthreads();
    #pragma unroll
    for (int i = 0; i < 16; ++i) {
      int e = t + i*256;
      int d = e >> 6, r = e & 63;
      Wob[(size_t)(n0+d)*1024 + k0 + r] = tile[d*65 + r];
    }
  }
}

// ---- GEMM: 256x256x64, m201-style 4-phase/K-step pipeline (T2+T3+T4+T5) ----
// 512 thr = 8 waves (2M x 4N), per-wave C = 128x64. LDS: 2 dbuf x A[256][64] +
// B[256][64], XOR-chunk swizzle (slot = chunk ^ (row&7)) applied on staging
// SOURCE and ds_read addr (both-sides, rule #21); gld_lds dest linear.
// Staging granularity: 8 quarter-units (64 rows, 1 gload/thread) per K-step,
// order [A-q0,A-q2 | B-q0,B-q1 | B-q2,B-q3 | A-q1,A-q3] across the 4 phases.
// Counted waits only: vmcnt(4) end of P1 (covers P2's A-qm1 reads),
// vmcnt(2) end of P3 (covers next step's P0 reads; leaves P3 stages in
// flight). Never vmcnt(0) in the loop. 24 ds_read_b128/step (minimal: B regs
// cached across phases, A per half). setprio(1) around each 16-MFMA cluster.
// MODE 0: N=3072 QKV proj -> Q (x0.125*log2e) [bh][s][d], K [bh][s][d],
//         V transposed [bh][d][s].  MODE 1: N=1024 out proj -> fp32.
template<int MODE>
__global__ __launch_bounds__(512, 2) void gemm8p_kern(
    const ushort* __restrict__ A,
    const ushort* __restrict__ Bw,
    const float* __restrict__ bias,
    ushort* __restrict__ Qb, ushort* __restrict__ Kb, ushort* __restrict__ Vtb,
    float* __restrict__ outF)
{
  constexpr int NT  = (MODE==0) ? 12 : 4;   // n-tiles of 256
  constexpr int CHK = 4*NT;                 // blocks per XCD chunk

  __shared__ __align__(16) ushort As[2][16384];   // [dbuf][(row 0..255)*64+col]
  __shared__ __align__(16) ushort Bs[2][16384];

  const int t = threadIdx.x;
  const int l = t & 63, w = t >> 6;
  const int wr = w >> 2, wc = w & 3;
  const int li = l & 15, c4 = l >> 4;
  const int srow = t >> 3, sj = (t & 7) ^ ((t >> 3) & 7);   // staging row/src-chunk

  // raster: m-supertiles of 4 x all-n, bijective XCD chunking
  const int swz = (blockIdx.x & 7) * CHK + (blockIdx.x >> 3);
  const int ms = swz / CHK, rem = swz % CHK;
  const int m0 = (ms*4 + (rem & 3)) * 256;
  const int n0 = (rem >> 2) * 256;

  f32x4 acc[8][4];
  #pragma unroll
  for (int i=0;i<8;i++)
    #pragma unroll
    for (int j=0;j<4;j++) acc[i][j] = (f32x4)0.0f;

  auto SA = [&](int buf, int u, int kk) {
    gld16(&A[(size_t)(m0 + u*64 + srow)*1024 + kk + sj*8], &As[buf][u*4096 + t*8]);
  };
  auto SB = [&](int buf, int u, int kk) {
    gld16(&Bw[(size_t)(n0 + u*64 + srow)*1024 + kk + sj*8], &Bs[buf][u*4096 + t*8]);
  };

  // prologue: stage K-step 0, oldest-first = first-consumed
  SB(0,0,0); SB(0,1,0); SB(0,2,0); SB(0,3,0);
  SA(0,0,0); SA(0,2,0); SA(0,1,0); SA(0,3,0);
  asm volatile("s_waitcnt vmcnt(2)" ::: "memory");
  __builtin_amdgcn_s_barrier();
  __builtin_amdgcn_sched_barrier(0);

  #pragma unroll 2
  for (int kt = 0; kt < 16; ++kt) {
    const int c = kt & 1, nb = c ^ 1;
    const int kk = (kt + 1 < 16) ? (kt + 1) * 64 : 0;   // tail: dummy restage
    short8 af[4][2], bf[4][2];

    // ---------------- P0: reads (A qm0 + all B) + stage A-q0,A-q2 ----------
    #pragma unroll
    for (int i=0;i<4;i++)
      #pragma unroll
      for (int ks=0;ks<2;ks++)
        af[i][ks] = *(const short8*)&As[c][(wr*128 + i*16 + li)*64 + (((ks*4+c4)^(li&7))*8)];
    #pragma unroll
    for (int j=0;j<4;j++)
      #pragma unroll
      for (int ks=0;ks<2;ks++)
        bf[j][ks] = *(const short8*)&Bs[c][(wc*64 + j*16 + li)*64 + (((ks*4+c4)^(li&7))*8)];
    SA(nb, 0, kk); SA(nb, 2, kk);
    __builtin_amdgcn_s_barrier();
    asm volatile("s_waitcnt lgkmcnt(0)" ::: "memory");
    __builtin_amdgcn_sched_barrier(0);
    __builtin_amdgcn_s_setprio(1);
    #pragma unroll
    for (int i=0;i<4;i++)
      #pragma unroll
      for (int jj=0;jj<2;jj++)
        #pragma unroll
        for (int ks=0;ks<2;ks++)
          acc[i][jj] = __builtin_amdgcn_mfma_f32_16x16x32_bf16(af[i][ks], bf[jj][ks], acc[i][jj], 0,0,0);
    __builtin_amdgcn_s_setprio(0);
    __builtin_amdgcn_s_barrier();
    __builtin_amdgcn_sched_barrier(0);

    // ---------------- P1: stage B-q0,B-q1; MFMA (qm0, qn1) ------------------
    SB(nb, 0, kk); SB(nb, 1, kk);
    __builtin_amdgcn_s_barrier();
    __builtin_amdgcn_sched_barrier(0);
    __builtin_amdgcn_s_setprio(1);
    #pragma unroll
    for (int i=0;i<4;i++)
      #pragma unroll
      for (int jj=0;jj<2;jj++)
        #pragma unroll
        for (int ks=0;ks<2;ks++)
          acc[i][2+jj] = __builtin_amdgcn_mfma_f32_16x16x32_bf16(af[i][ks], bf[2+jj][ks], acc[i][2+jj], 0,0,0);
    __builtin_amdgcn_s_setprio(0);
    asm volatile("s_waitcnt vmcnt(4)" ::: "memory");   // A-q1,A-q3 of THIS step landed
    __builtin_amdgcn_s_barrier();
    __builtin_amdgcn_sched_barrier(0);

    // ---------------- P2: reads (A qm1) + stage B-q2,B-q3 -------------------
    #pragma unroll
    for (int i=0;i<4;i++)
      #pragma unroll
      for (int ks=0;ks<2;ks++)
        af[i][ks] = *(const short8*)&As[c][(wr*128 + (4+i)*16 + li)*64 + (((ks*4+c4)^(li&7))*8)];
    SB(nb, 2, kk); SB(nb, 3, kk);
    __builtin_amdgcn_s_barrier();
    asm volatile("s_waitcnt lgkmcnt(0)" ::: "memory");
    __builtin_amdgcn_sched_barrier(0);
    __builtin_amdgcn_s_setprio(1);
    #pragma unroll
    for (int i=0;i<4;i++)
      #pragma unroll
      for (int jj=0;jj<2;jj++)
        #pragma unroll
        for (int ks=0;ks<2;ks++)
          acc[4+i][jj] = __builtin_amdgcn_mfma_f32_16x16x32_bf16(af[i][ks], bf[jj][ks], acc[4+i][jj], 0,0,0);
    __builtin_amdgcn_s_setprio(0);
    __builtin_amdgcn_s_barrier();
    __builtin_amdgcn_sched_barrier(0);

    // ---------------- P3: stage A-q1,A-q3; MFMA (qm1, qn1) ------------------
    SA(nb, 1, kk); SA(nb, 3, kk);
    __builtin_amdgcn_s_barrier();
    __builtin_amdgcn_sched_barrier(0);
    __builtin_amdgcn_s_setprio(1);
    #pragma unroll
    for (int i=0;i<4;i++)
      #pragma unroll
      for (int jj=0;jj<2;jj++)
        #pragma unroll
        for (int ks=0;ks<2;ks++)
          acc[4+i][2+jj] = __builtin_amdgcn_mfma_f32_16x16x32_bf16(af[i][ks], bf[2+jj][ks], acc[4+i][2+jj], 0,0,0);
    __builtin_amdgcn_s_setprio(0);
    asm volatile("s_waitcnt vmcnt(2)" ::: "memory");   // next step's P0 data landed
    __builtin_amdgcn_s_barrier();
    __builtin_amdgcn_sched_barrier(0);
  }

  #pragma unroll
  for (int i=0;i<8;i++) {
    int rbase = m0 + wr*128 + i*16 + c4*4;
    #pragma unroll
    for (int j=0;j<4;j++) {
      int col = n0 + wc*64 + j*16 + li;
      float bv = bias[col];
      if (MODE == 0) {
        int p = col >> 10, h = (col >> 6) & 15, d = col & 63;
        int b = rbase >> 10, s = rbase & 1023;
        if (p == 2) {          // V -> transposed [bh][d][s], 8B packed store
          ushort pk4[4];
          #pragma unroll
          for (int r=0;r<4;r++) pk4[r] = f2b(acc[i][j][r] + bv);
          *(uint2*)&Vtb[((size_t)((b*16+h)*64 + d))*1024 + s] = *(uint2*)pk4;
        } else {
          ushort* dst = (p==0) ? Qb : Kb;
          float sc = (p==0) ? 0.18033688011112042f : 1.0f;   // 0.125*log2(e)
          #pragma unroll
          for (int r=0;r<4;r++)
            dst[(((size_t)(b*16 + h))*1024 + s + r)*64 + d] = f2b((acc[i][j][r] + bv) * sc);
        }
      } else {
        #pragma unroll
        for (int r=0;r<4;r++)
          outF[(size_t)(rbase+r)*1024 + col] = acc[i][j][r] + bv;
      }
    }
  }
}

// ---------------- causal flash attention, wave-independent ----------------
// 1024 blocks x 256 thr; wave w handles q-tile {j,15-j,16+j,31-j}[w] of head bh.
// No __syncthreads. 32x32x16 MFMAs; swapped QK^T (S[kv][q]) and swapped PV
// (O[d][q]) so softmax state is per-lane scalar + one shfl_xor(32).
// Scores in log2 domain (scale folded into Q).
__global__ __launch_bounds__(256, 3) void attn_kern(
    const ushort* __restrict__ Qb, const ushort* __restrict__ Kb,
    const ushort* __restrict__ Vt, ushort* __restrict__ Ob)
{
  __shared__ __align__(16) ushort Pb[4][32*40];   // per-wave P [q][kv], stride 40
  __shared__ __align__(16) ushort OT[4][32*72];   // per-wave epilogue transpose
  const int t = threadIdx.x, l = t & 63, w = t >> 6;
  const int bid = blockIdx.x;
  const int x = bid & 7, i0 = bid >> 3;
  const int bh = x*16 + (i0 >> 3), j = i0 & 7;     // bh clustered per XCD
  int qt;
  if      (w == 0) qt = j;
  else if (w == 1) qt = 15 - j;
  else if (w == 2) qt = 16 + j;
  else             qt = 31 - j;

  const int col = l & 31, hi = l >> 5;
  const ushort* Qp = Qb + (size_t)bh*65536;
  const ushort* Kp = Kb + (size_t)bh*65536;
  const ushort* Vp = Vt + (size_t)bh*65536;

  short8 qf[4];
  #pragma unroll
  for (int m=0;m<4;m++)
    qf[m] = *(const short8*)&Qp[(size_t)(qt*32+col)*64 + m*16 + hi*8];

  f32x16 accO0 = (f32x16)0.0f, accO1 = (f32x16)0.0f;
  float mR = -1e30f, lS = 0.0f;

  ushort* Pw = &Pb[w][0];
  const int nt = qt + 1;
  for (int kt = 0; kt < nt; ++kt) {
    short8 kf[4], vf0[2], vf1[2];
    #pragma unroll
    for (int m=0;m<4;m++)
      kf[m] = *(const short8*)&Kp[(size_t)(kt*32+col)*64 + m*16 + hi*8];
    #pragma unroll
    for (int m=0;m<2;m++) {
      vf0[m] = *(const short8*)&Vp[(size_t)col*1024      + kt*32 + m*16 + hi*8];
      vf1[m] = *(const short8*)&Vp[(size_t)(32+col)*1024 + kt*32 + m*16 + hi*8];
    }

    f32x16 s = (f32x16)0.0f;
    #pragma unroll
    for (int m=0;m<4;m++)
      s = __builtin_amdgcn_mfma_f32_32x32x16_bf16(kf[m], qf[m], s, 0, 0, 0);

    if (kt == qt) {                       // diagonal tile: causal mask
      #pragma unroll
      for (int r=0;r<16;r++) {
        int kvl = (r&3) + ((r>>2)<<3) + 4*hi;
        s[r] = (kvl > col) ? -1e9f : s[r];
      }
    }

    float mx = s[0];
    #pragma unroll
    for (int r=1;r<16;r++) mx = fmaxf(mx, s[r]);
    mx = fmaxf(mx, __shfl_xor(mx, 32));   // combine kv-halves (lane i <-> i+32)

    if (__any(mx - mR > 8.0f)) {          // T13 defer-max (log2 units)
      float mN = fmaxf(mR, mx);
      float corr = __builtin_amdgcn_exp2f(mR - mN);
      mR = mN; lS *= corr;
      #pragma unroll
      for (int r=0;r<16;r++) { accO0[r] *= corr; accO1[r] *= corr; }
    }

    float p[16], rs = 0.0f;
    #pragma unroll
    for (int r=0;r<16;r++) { p[r] = __builtin_amdgcn_exp2f(s[r] - mR); rs += p[r]; }
    rs += __shfl_xor(rs, 32);
    lS += rs;

    // P -> per-wave LDS [q][kv] (packed pair writes), then B-fragment reads
    #pragma unroll
    for (int r2=0;r2<8;r2++) {
      int r = 2*r2;
      int kv = (r&3) + ((r>>2)<<3) + 4*hi;          // even; pair (kv, kv+1)
      *(unsigned*)&Pw[col*40 + kv] = pk2(p[r], p[r+1]);
    }
    short8 pb0 = *(const short8*)&Pw[col*40 + hi*8];        // kv 0..15 slice
    short8 pb1 = *(const short8*)&Pw[col*40 + 16 + hi*8];   // kv 16..31 slice

    accO0 = __builtin_amdgcn_mfma_f32_32x32x16_bf16(vf0[0], pb0, accO0, 0,0,0);
    accO0 = __builtin_amdgcn_mfma_f32_32x32x16_bf16(vf0[1], pb1, accO0, 0,0,0);
    accO1 = __builtin_amdgcn_mfma_f32_32x32x16_bf16(vf1[0], pb0, accO1, 0,0,0);
    accO1 = __builtin_amdgcn_mfma_f32_32x32x16_bf16(vf1[1], pb1, accO1, 0,0,0);
  }

  // epilogue: O[dv][q] regs -> LDS transpose -> coalesced global store
  float inv = 1.0f / lS;
  ushort* o = &OT[w][0];
  #pragma unroll
  for (int r2=0;r2<8;r2++) {
    int r = 2*r2;
    int dv = (r&3) + ((r>>2)<<3) + 4*hi;
    *(unsigned*)&o[col*72 + dv]      = pk2(accO0[r]*inv, accO0[r+1]*inv);
    *(unsigned*)&o[col*72 + 32 + dv] = pk2(accO1[r]*inv, accO1[r+1]*inv);
  }
  const int b = bh >> 4, h = bh & 15;
  #pragma unroll
  for (int it=0; it<4; ++it) {
    int q = it*8 + (l>>3), c8 = (l&7)*8;
    uint4 v = *(const uint4*)&o[q*72 + c8];
    int qg = qt*32 + q;
    *(uint4*)&Ob[(size_t)(b*1024+qg)*1024 + h*64 + c8] = v;
  }
}

extern "C" void kernel_launch(void* const* d_in, const int* in_sizes, int n_in,
                              void* d_out, int out_size, void* d_ws, size_t ws_size,
                              hipStream_t stream) {
  const float* query = (const float*)d_in[0];
  const float* Wq = (const float*)d_in[4];
  const float* bq = (const float*)d_in[5];
  const float* Wk = (const float*)d_in[6];
  const float* bk = (const float*)d_in[7];
  const float* Wv = (const float*)d_in[8];
  const float* bv = (const float*)d_in[9];
  const float* Wo = (const float*)d_in[10];
  const float* bo = (const float*)d_in[11];

  char* wsb = (char*)d_ws;
  ushort* Xb   = (ushort*)(wsb);                  // 16 MB
  ushort* Wqkv = (ushort*)(wsb + 16777216);       // 6 MB
  float*  Bqkv = (float*) (wsb + 23068672);       // 12 KB
  ushort* Wob  = (ushort*)(wsb + 23080960);       // 2 MB
  ushort* Qb   = (ushort*)(wsb + 25178112);       // 16 MB
  ushort* Kb   = (ushort*)(wsb + 41955328);       // 16 MB
  ushort* Vtb  = (ushort*)(wsb + 58732544);       // 16 MB  [bh][d][s]
  ushort* Ob   = (ushort*)(wsb + 75509760);       // 16 MB

  hipLaunchKernelGGL(pack_x_kern, dim3(4096), dim3(256), 0, stream, query, Xb);
  hipLaunchKernelGGL(pack_w_kern, dim3(1024), dim3(256), 0, stream,
                     Wq, Wk, Wv, bq, bk, bv, Wo, Wqkv, Bqkv, Wob);
  hipLaunchKernelGGL(gemm8p_kern<0>, dim3(384), dim3(512), 0, stream,
                     Xb, Wqkv, Bqkv, Qb, Kb, Vtb, (float*)nullptr);
  hipLaunchKernelGGL(attn_kern, dim3(1024), dim3(256), 0, stream, Qb, Kb, Vtb, Ob);
  hipLaunchKernelGGL(gemm8p_kern<1>, dim3(128), dim3(512), 0, stream,
                     Ob, Wob, bo, (ushort*)nullptr, (ushort*)nullptr, (ushort*)nullptr,
                     (float*)d_out);
}

// Round 9
// 168.270 us; speedup vs baseline: 1.0957x; 1.0957x over previous
//
#include <hip/hip_runtime.h>
#include <hip/hip_bf16.h>

#define B_ 8
#define S_ 1024
#define U_ 1024
#define H_ 16
#define DK_ 64

typedef __attribute__((ext_vector_type(8))) short short8;
typedef __attribute__((ext_vector_type(4))) float f32x4;
typedef __attribute__((ext_vector_type(16))) float f32x16;

__device__ inline ushort f2b(float x) {
  union { float f; unsigned u; } v; v.f = x;
  unsigned r = (v.u + 0x7FFFu + ((v.u >> 16) & 1u)) >> 16;
  return (ushort)r;
}
__device__ inline unsigned pk2(float lo, float hi) {
  return (unsigned)f2b(lo) | ((unsigned)f2b(hi) << 16);
}

__device__ inline void gld16(const ushort* g, ushort* l) {
  __builtin_amdgcn_global_load_lds((__attribute__((address_space(1))) void*)(g),
                                   (__attribute__((address_space(3))) void*)(l),
                                   16, 0, 0);
}

// ---------------- pack query fp32 -> bf16 ----------------
__global__ __launch_bounds__(256) void pack_x_kern(const float* __restrict__ X,
                                                   ushort* __restrict__ Xb) {
  int idx = blockIdx.x * 256 + threadIdx.x;
  const float4* src = (const float4*)X + (size_t)idx * 2;
  float4 a = src[0], b = src[1];
  ushort r[8];
  r[0]=f2b(a.x); r[1]=f2b(a.y); r[2]=f2b(a.z); r[3]=f2b(a.w);
  r[4]=f2b(b.x); r[5]=f2b(b.y); r[6]=f2b(b.z); r[7]=f2b(b.w);
  *(uint4*)(Xb + (size_t)idx*8) = *(uint4*)r;
}

// ---------------- pack weights (transpose to [n][k], bf16) ----------------
__global__ __launch_bounds__(256) void pack_w_kern(
    const float* __restrict__ Wq, const float* __restrict__ Wk, const float* __restrict__ Wv,
    const float* __restrict__ bq, const float* __restrict__ bk, const float* __restrict__ bv,
    const float* __restrict__ Wo,
    ushort* __restrict__ Wqkv, float* __restrict__ Bqkv, ushort* __restrict__ Wob)
{
  __shared__ ushort tile[64*65];
  const int t = threadIdx.x;
  const int bid = blockIdx.x;
  if (bid < 768) {
    int p = bid >> 8, rem = bid & 255;
    int h = rem >> 4, kc = rem & 15, k0 = kc*64;
    const float* Wsrc = (p==0) ? Wq : ((p==1) ? Wk : Wv);
    #pragma unroll
    for (int i = 0; i < 16; ++i) {
      int e = t + i*256;
      int r = e >> 6, d = e & 63;
      tile[d*65 + r] = f2b(Wsrc[h*65536 + (k0+r)*64 + d]);
    }
    __syncthreads();
    #pragma unroll
    for (int i = 0; i < 16; ++i) {
      int e = t + i*256;
      int d = e >> 6, r = e & 63;
      Wqkv[(size_t)(p*1024 + h*64 + d)*1024 + k0 + r] = tile[d*65 + r];
    }
    if (kc == 0 && t < 64) {
      const float* bsrc = (p==0) ? bq : ((p==1) ? bk : bv);
      Bqkv[p*1024 + h*64 + t] = bsrc[h*64 + t];
    }
  } else {
    int b2 = bid - 768;
    int nc = b2 >> 4, kc = b2 & 15;
    int n0 = nc*64, k0 = kc*64;
    #pragma unroll
    for (int i = 0; i < 16; ++i) {
      int e = t + i*256;
      int r = e >> 6, d = e & 63;
      tile[d*65 + r] = f2b(Wo[(size_t)(k0+r)*1024 + n0 + d]);
    }
    __syncthreads();
    #pragma unroll
    for (int i = 0; i < 16; ++i) {
      int e = t + i*256;
      int d = e >> 6, r = e & 63;
      Wob[(size_t)(n0+d)*1024 + k0 + r] = tile[d*65 + r];
    }
  }
}

// ---- GEMM: 128x128x64, dbuf + counted vmcnt, 2 blocks/CU (T2+T4+T5) --------
// 256 thr = 4 waves (2M x 2N), per-wave C = 64x64 (4x4 16x16 frags). LDS:
// 2 dbuf x (A[128][64] + B[128][64]) = 64 KB -> 2 blocks/CU co-resident (the
// cross-block overlap rounds 6-8 lacked at 1 blk/CU). Grid 1536 (MODE0) =
// exactly 3 rounds of 512 resident -> zero tail. XOR-chunk swizzle both-sides
// (proven 0-conflict). Per K-tile: {ds_read 16 frags, setprio1, 32 MFMA,
// setprio0, s_barrier, stage tile t+2 (8 gld_lds), vmcnt(8) [counted: waits
// only tile t+1, leaves t+2 in flight through next MFMA phase], s_barrier}.
// Never vmcnt(0) in loop.
// MODE 0: N=3072 QKV proj -> Q (x0.125*log2e) [bh][s][d], K [bh][s][d],
//         V transposed [bh][d][s].  MODE 1: N=1024 out proj -> fp32.
template<int MODE>
__global__ __launch_bounds__(256, 2) void gemm128_kern(
    const ushort* __restrict__ A,
    const ushort* __restrict__ Bw,
    const float* __restrict__ bias,
    ushort* __restrict__ Qb, ushort* __restrict__ Kb, ushort* __restrict__ Vtb,
    float* __restrict__ outF)
{
  __shared__ __align__(16) ushort As[2][8192];   // [dbuf][(row 0..127)*64+col]
  __shared__ __align__(16) ushort Bs[2][8192];

  const int t = threadIdx.x;
  const int l = t & 63, w = t >> 6;
  const int wr = w >> 1, wc = w & 1;
  const int li = l & 15, c4 = l >> 4;

  // raster: m-supertiles of 8 x all-n, bijective XCD chunking
  int m0, n0;
  if (MODE==0) {      // 1536 blocks = 64m x 24n; chunk 192 = 8m x 24n
    int swz = (blockIdx.x & 7) * 192 + (blockIdx.x >> 3);
    int ms = swz / 192, rem = swz % 192;
    m0 = (ms*8 + (rem & 7)) * 128;  n0 = (rem >> 3) * 128;
  } else {            // 512 blocks = 64m x 8n; chunk 64 = 8m x 8n
    int swz = (blockIdx.x & 7) * 64 + (blockIdx.x >> 3);
    int ms = swz / 64, rem = swz % 64;
    m0 = (ms*8 + (rem & 7)) * 128;  n0 = (rem >> 3) * 128;
  }

  f32x4 acc[4][4];
  #pragma unroll
  for (int i=0;i<4;i++)
    #pragma unroll
    for (int j=0;j<4;j++) acc[i][j] = (f32x4)0.0f;

  // stage one 128x64 tile (1024 16B-chunks, 4/thread); source chunk
  // XOR-permuted within the 128B row, LDS dest linear (rule #21 both-sides)
  auto SA = [&](int buf, int kk) {
    #pragma unroll
    for (int p=0;p<4;++p) {
      int n = p*256 + t;
      int row = n >> 3, jj = (n & 7) ^ (row & 7);
      gld16(&A[(size_t)(m0 + row)*1024 + kk + jj*8], &As[buf][n*8]);
    }
  };
  auto SB = [&](int buf, int kk) {
    #pragma unroll
    for (int p=0;p<4;++p) {
      int n = p*256 + t;
      int row = n >> 3, jj = (n & 7) ^ (row & 7);
      gld16(&Bw[(size_t)(n0 + row)*1024 + kk + jj*8], &Bs[buf][n*8]);
    }
  };

  // prologue: tiles 0,1
  SA(0, 0);  SB(0, 0);
  SA(1, 64); SB(1, 64);
  asm volatile("s_waitcnt vmcnt(8)" ::: "memory");   // tile 0 landed
  __builtin_amdgcn_s_barrier();
  __builtin_amdgcn_sched_barrier(0);

  for (int kt = 0; kt < 16; ++kt) {
    const int cur = kt & 1;
    short8 af[4][2], bf[4][2];
    #pragma unroll
    for (int i=0;i<4;i++) {
      int rA = wr*64 + i*16 + li;
      int rB = wc*64 + i*16 + li;
      #pragma unroll
      for (int ks=0;ks<2;ks++) {
        af[i][ks] = *(const short8*)&As[cur][rA*64 + (((ks*4+c4)^(li&7))*8)];
        bf[i][ks] = *(const short8*)&Bs[cur][rB*64 + (((ks*4+c4)^(li&7))*8)];
      }
    }
    __builtin_amdgcn_s_setprio(1);
    #pragma unroll
    for (int i=0;i<4;i++)
      #pragma unroll
      for (int j=0;j<4;j++)
        #pragma unroll
        for (int ks=0;ks<2;ks++)
          acc[i][j] = __builtin_amdgcn_mfma_f32_16x16x32_bf16(af[i][ks], bf[j][ks], acc[i][j], 0,0,0);
    __builtin_amdgcn_s_setprio(0);

    __builtin_amdgcn_s_barrier();            // all waves done reading buf[cur]
    __builtin_amdgcn_sched_barrier(0);
    const int kk2 = ((kt + 2) & 15) * 64;    // tail wraps: dummy, never read
    SA(cur, kk2); SB(cur, kk2);
    asm volatile("s_waitcnt vmcnt(8)" ::: "memory");  // tile kt+1 landed; t+2 in flight
    __builtin_amdgcn_s_barrier();
    __builtin_amdgcn_sched_barrier(0);
  }

  #pragma unroll
  for (int i=0;i<4;i++) {
    int rbase = m0 + wr*64 + i*16 + c4*4;
    #pragma unroll
    for (int j=0;j<4;j++) {
      int col = n0 + wc*64 + j*16 + li;
      float bv = bias[col];
      if (MODE == 0) {
        int p = col >> 10, h = (col >> 6) & 15, d = col & 63;
        int b = rbase >> 10, s = rbase & 1023;
        if (p == 2) {          // V -> transposed [bh][d][s], 8B packed store
          ushort pk4[4];
          #pragma unroll
          for (int r=0;r<4;r++) pk4[r] = f2b(acc[i][j][r] + bv);
          *(uint2*)&Vtb[((size_t)((b*16+h)*64 + d))*1024 + s] = *(uint2*)pk4;
        } else {
          ushort* dst = (p==0) ? Qb : Kb;
          float sc = (p==0) ? 0.18033688011112042f : 1.0f;   // 0.125*log2(e)
          #pragma unroll
          for (int r=0;r<4;r++)
            dst[(((size_t)(b*16 + h))*1024 + s + r)*64 + d] = f2b((acc[i][j][r] + bv) * sc);
        }
      } else {
        #pragma unroll
        for (int r=0;r<4;r++)
          outF[(size_t)(rbase+r)*1024 + col] = acc[i][j][r] + bv;
      }
    }
  }
}

// ---------------- causal flash attention, wave-independent ----------------
// 1024 blocks x 256 thr; wave w handles q-tile {j,15-j,16+j,31-j}[w] of head bh.
// No __syncthreads. 32x32x16 MFMAs; swapped QK^T (S[kv][q]) and swapped PV
// (O[d][q]) so softmax state is per-lane scalar + one shfl_xor(32).
// Scores in log2 domain (scale folded into Q).
__global__ __launch_bounds__(256, 3) void attn_kern(
    const ushort* __restrict__ Qb, const ushort* __restrict__ Kb,
    const ushort* __restrict__ Vt, ushort* __restrict__ Ob)
{
  __shared__ __align__(16) ushort Pb[4][32*40];   // per-wave P [q][kv], stride 40
  __shared__ __align__(16) ushort OT[4][32*72];   // per-wave epilogue transpose
  const int t = threadIdx.x, l = t & 63, w = t >> 6;
  const int bid = blockIdx.x;
  const int x = bid & 7, i0 = bid >> 3;
  const int bh = x*16 + (i0 >> 3), j = i0 & 7;     // bh clustered per XCD
  int qt;
  if      (w == 0) qt = j;
  else if (w == 1) qt = 15 - j;
  else if (w == 2) qt = 16 + j;
  else             qt = 31 - j;

  const int col = l & 31, hi = l >> 5;
  const ushort* Qp = Qb + (size_t)bh*65536;
  const ushort* Kp = Kb + (size_t)bh*65536;
  const ushort* Vp = Vt + (size_t)bh*65536;

  short8 qf[4];
  #pragma unroll
  for (int m=0;m<4;m++)
    qf[m] = *(const short8*)&Qp[(size_t)(qt*32+col)*64 + m*16 + hi*8];

  f32x16 accO0 = (f32x16)0.0f, accO1 = (f32x16)0.0f;
  float mR = -1e30f, lS = 0.0f;

  ushort* Pw = &Pb[w][0];
  const int nt = qt + 1;
  for (int kt = 0; kt < nt; ++kt) {
    short8 kf[4], vf0[2], vf1[2];
    #pragma unroll
    for (int m=0;m<4;m++)
      kf[m] = *(const short8*)&Kp[(size_t)(kt*32+col)*64 + m*16 + hi*8];
    #pragma unroll
    for (int m=0;m<2;m++) {
      vf0[m] = *(const short8*)&Vp[(size_t)col*1024      + kt*32 + m*16 + hi*8];
      vf1[m] = *(const short8*)&Vp[(size_t)(32+col)*1024 + kt*32 + m*16 + hi*8];
    }

    f32x16 s = (f32x16)0.0f;
    #pragma unroll
    for (int m=0;m<4;m++)
      s = __builtin_amdgcn_mfma_f32_32x32x16_bf16(kf[m], qf[m], s, 0, 0, 0);

    if (kt == qt) {                       // diagonal tile: causal mask
      #pragma unroll
      for (int r=0;r<16;r++) {
        int kvl = (r&3) + ((r>>2)<<3) + 4*hi;
        s[r] = (kvl > col) ? -1e9f : s[r];
      }
    }

    float mx = s[0];
    #pragma unroll
    for (int r=1;r<16;r++) mx = fmaxf(mx, s[r]);
    mx = fmaxf(mx, __shfl_xor(mx, 32));   // combine kv-halves (lane i <-> i+32)

    if (__any(mx - mR > 8.0f)) {          // T13 defer-max (log2 units)
      float mN = fmaxf(mR, mx);
      float corr = __builtin_amdgcn_exp2f(mR - mN);
      mR = mN; lS *= corr;
      #pragma unroll
      for (int r=0;r<16;r++) { accO0[r] *= corr; accO1[r] *= corr; }
    }

    float p[16], rs = 0.0f;
    #pragma unroll
    for (int r=0;r<16;r++) { p[r] = __builtin_amdgcn_exp2f(s[r] - mR); rs += p[r]; }
    rs += __shfl_xor(rs, 32);
    lS += rs;

    // P -> per-wave LDS [q][kv] (packed pair writes), then B-fragment reads
    #pragma unroll
    for (int r2=0;r2<8;r2++) {
      int r = 2*r2;
      int kv = (r&3) + ((r>>2)<<3) + 4*hi;          // even; pair (kv, kv+1)
      *(unsigned*)&Pw[col*40 + kv] = pk2(p[r], p[r+1]);
    }
    short8 pb0 = *(const short8*)&Pw[col*40 + hi*8];        // kv 0..15 slice
    short8 pb1 = *(const short8*)&Pw[col*40 + 16 + hi*8];   // kv 16..31 slice

    accO0 = __builtin_amdgcn_mfma_f32_32x32x16_bf16(vf0[0], pb0, accO0, 0,0,0);
    accO0 = __builtin_amdgcn_mfma_f32_32x32x16_bf16(vf0[1], pb1, accO0, 0,0,0);
    accO1 = __builtin_amdgcn_mfma_f32_32x32x16_bf16(vf1[0], pb0, accO1, 0,0,0);
    accO1 = __builtin_amdgcn_mfma_f32_32x32x16_bf16(vf1[1], pb1, accO1, 0,0,0);
  }

  // epilogue: O[dv][q] regs -> LDS transpose -> coalesced global store
  float inv = 1.0f / lS;
  ushort* o = &OT[w][0];
  #pragma unroll
  for (int r2=0;r2<8;r2++) {
    int r = 2*r2;
    int dv = (r&3) + ((r>>2)<<3) + 4*hi;
    *(unsigned*)&o[col*72 + dv]      = pk2(accO0[r]*inv, accO0[r+1]*inv);
    *(unsigned*)&o[col*72 + 32 + dv] = pk2(accO1[r]*inv, accO1[r+1]*inv);
  }
  const int b = bh >> 4, h = bh & 15;
  #pragma unroll
  for (int it=0; it<4; ++it) {
    int q = it*8 + (l>>3), c8 = (l&7)*8;
    uint4 v = *(const uint4*)&o[q*72 + c8];
    int qg = qt*32 + q;
    *(uint4*)&Ob[(size_t)(b*1024+qg)*1024 + h*64 + c8] = v;
  }
}

extern "C" void kernel_launch(void* const* d_in, const int* in_sizes, int n_in,
                              void* d_out, int out_size, void* d_ws, size_t ws_size,
                              hipStream_t stream) {
  const float* query = (const float*)d_in[0];
  const float* Wq = (const float*)d_in[4];
  const float* bq = (const float*)d_in[5];
  const float* Wk = (const float*)d_in[6];
  const float* bk = (const float*)d_in[7];
  const float* Wv = (const float*)d_in[8];
  const float* bv = (const float*)d_in[9];
  const float* Wo = (const float*)d_in[10];
  const float* bo = (const float*)d_in[11];

  char* wsb = (char*)d_ws;
  ushort* Xb   = (ushort*)(wsb);                  // 16 MB
  ushort* Wqkv = (ushort*)(wsb + 16777216);       // 6 MB
  float*  Bqkv = (float*) (wsb + 23068672);       // 12 KB
  ushort* Wob  = (ushort*)(wsb + 23080960);       // 2 MB
  ushort* Qb   = (ushort*)(wsb + 25178112);       // 16 MB
  ushort* Kb   = (ushort*)(wsb + 41955328);       // 16 MB
  ushort* Vtb  = (ushort*)(wsb + 58732544);       // 16 MB  [bh][d][s]
  ushort* Ob   = (ushort*)(wsb + 75509760);       // 16 MB

  hipLaunchKernelGGL(pack_x_kern, dim3(4096), dim3(256), 0, stream, query, Xb);
  hipLaunchKernelGGL(pack_w_kern, dim3(1024), dim3(256), 0, stream,
                     Wq, Wk, Wv, bq, bk, bv, Wo, Wqkv, Bqkv, Wob);
  hipLaunchKernelGGL(gemm128_kern<0>, dim3(1536), dim3(256), 0, stream,
                     Xb, Wqkv, Bqkv, Qb, Kb, Vtb, (float*)nullptr);
  hipLaunchKernelGGL(attn_kern, dim3(1024), dim3(256), 0, stream, Qb, Kb, Vtb, Ob);
  hipLaunchKernelGGL(gemm128_kern<1>, dim3(512), dim3(256), 0, stream,
                     Ob, Wob, bo, (ushort*)nullptr, (ushort*)nullptr, (ushort*)nullptr,
                     (float*)d_out);
}

// Round 10
// 167.783 us; speedup vs baseline: 1.0989x; 1.0029x over previous
//
#include <hip/hip_runtime.h>
#include <hip/hip_bf16.h>

#define B_ 8
#define S_ 1024
#define U_ 1024
#define H_ 16
#define DK_ 64

typedef __attribute__((ext_vector_type(8))) short short8;
typedef __attribute__((ext_vector_type(4))) float f32x4;
typedef __attribute__((ext_vector_type(16))) float f32x16;

__device__ inline ushort f2b(float x) {
  union { float f; unsigned u; } v; v.f = x;
  unsigned r = (v.u + 0x7FFFu + ((v.u >> 16) & 1u)) >> 16;
  return (ushort)r;
}
__device__ inline unsigned pk2(float lo, float hi) {
  return (unsigned)f2b(lo) | ((unsigned)f2b(hi) << 16);
}

__device__ inline void gld16(const ushort* g, ushort* l) {
  __builtin_amdgcn_global_load_lds((__attribute__((address_space(1))) void*)(g),
                                   (__attribute__((address_space(3))) void*)(l),
                                   16, 0, 0);
}

// ---------------- pack query fp32 -> bf16 ----------------
__global__ __launch_bounds__(256) void pack_x_kern(const float* __restrict__ X,
                                                   ushort* __restrict__ Xb) {
  int idx = blockIdx.x * 256 + threadIdx.x;
  const float4* src = (const float4*)X + (size_t)idx * 2;
  float4 a = src[0], b = src[1];
  ushort r[8];
  r[0]=f2b(a.x); r[1]=f2b(a.y); r[2]=f2b(a.z); r[3]=f2b(a.w);
  r[4]=f2b(b.x); r[5]=f2b(b.y); r[6]=f2b(b.z); r[7]=f2b(b.w);
  *(uint4*)(Xb + (size_t)idx*8) = *(uint4*)r;
}

// ---------------- pack weights (transpose to [n][k], bf16) ----------------
__global__ __launch_bounds__(256) void pack_w_kern(
    const float* __restrict__ Wq, const float* __restrict__ Wk, const float* __restrict__ Wv,
    const float* __restrict__ bq, const float* __restrict__ bk, const float* __restrict__ bv,
    const float* __restrict__ Wo,
    ushort* __restrict__ Wqkv, float* __restrict__ Bqkv, ushort* __restrict__ Wob)
{
  __shared__ ushort tile[64*65];
  const int t = threadIdx.x;
  const int bid = blockIdx.x;
  if (bid < 768) {
    int p = bid >> 8, rem = bid & 255;
    int h = rem >> 4, kc = rem & 15, k0 = kc*64;
    const float* Wsrc = (p==0) ? Wq : ((p==1) ? Wk : Wv);
    #pragma unroll
    for (int i = 0; i < 16; ++i) {
      int e = t + i*256;
      int r = e >> 6, d = e & 63;
      tile[d*65 + r] = f2b(Wsrc[h*65536 + (k0+r)*64 + d]);
    }
    __syncthreads();
    #pragma unroll
    for (int i = 0; i < 16; ++i) {
      int e = t + i*256;
      int d = e >> 6, r = e & 63;
      Wqkv[(size_t)(p*1024 + h*64 + d)*1024 + k0 + r] = tile[d*65 + r];
    }
    if (kc == 0 && t < 64) {
      const float* bsrc = (p==0) ? bq : ((p==1) ? bk : bv);
      Bqkv[p*1024 + h*64 + t] = bsrc[h*64 + t];
    }
  } else {
    int b2 = bid - 768;
    int nc = b2 >> 4, kc = b2 & 15;
    int n0 = nc*64, k0 = kc*64;
    #pragma unroll
    for (int i = 0; i < 16; ++i) {
      int e = t + i*256;
      int r = e >> 6, d = e & 63;
      tile[d*65 + r] = f2b(Wo[(size_t)(k0+r)*1024 + n0 + d]);
    }
    __syncthreads();
    #pragma unroll
    for (int i = 0; i < 16; ++i) {
      int e = t + i*256;
      int d = e >> 6, r = e & 63;
      Wob[(size_t)(n0+d)*1024 + k0 + r] = tile[d*65 + r];
    }
  }
}

// ---- GEMM: 128x128x32, dbuf + counted vmcnt, 4 blocks/CU (T2+T4+T5) --------
// 256 thr = 4 waves (2M x 2N). LDS: 2 dbuf x (A[128][32] + B[128][32]) = 32 KB
// -> 4 blocks/CU (cross-block latency hiding; m97 regime). Per K-tile:
// {vmcnt(4) [counted: tile kt landed, kt+1 in flight], s_barrier, ds_read 8
// frags, setprio1, 16 MFMA, setprio0, s_barrier, stage tile kt+2 (4 gld_lds)}.
// Never vmcnt(0) in loop. Swizzle: 16B-chunk slot = chunk ^ ((row>>1)&3),
// applied to staging SOURCE and ds_read addr (both-sides, rule #21).
// MODE 0: N=3072 QKV proj -> Q (x0.125*log2e) [bh][s][d], K [bh][s][d],
//         V transposed [bh][d][s].  MODE 1: N=1024 out proj -> fp32.
template<int MODE>
__global__ __launch_bounds__(256, 4) void gemm128_kern(
    const ushort* __restrict__ A,
    const ushort* __restrict__ Bw,
    const float* __restrict__ bias,
    ushort* __restrict__ Qb, ushort* __restrict__ Kb, ushort* __restrict__ Vtb,
    float* __restrict__ outF)
{
  __shared__ __align__(16) ushort As[2][4096];   // [dbuf][(row 0..127)*32+col]
  __shared__ __align__(16) ushort Bs[2][4096];

  const int t = threadIdx.x;
  const int l = t & 63, w = t >> 6;
  const int wr = w >> 1, wc = w & 1;
  const int li = l & 15, c4 = l >> 4;

  // raster: m-supertiles of 8 x all-n, bijective XCD chunking
  int m0, n0;
  if (MODE==0) {      // 1536 blocks = 64m x 24n; chunk 192 = 8m x 24n
    int swz = (blockIdx.x & 7) * 192 + (blockIdx.x >> 3);
    int ms = swz / 192, rem = swz % 192;
    m0 = (ms*8 + (rem & 7)) * 128;  n0 = (rem >> 3) * 128;
  } else {            // 512 blocks = 64m x 8n; chunk 64 = 8m x 8n
    int swz = (blockIdx.x & 7) * 64 + (blockIdx.x >> 3);
    int ms = swz / 64, rem = swz % 64;
    m0 = (ms*8 + (rem & 7)) * 128;  n0 = (rem >> 3) * 128;
  }

  f32x4 acc[4][4];
  #pragma unroll
  for (int i=0;i<4;i++)
    #pragma unroll
    for (int j=0;j<4;j++) acc[i][j] = (f32x4)0.0f;

  // stage one 128x32 tile (512 16B-chunks, 2/thread per matrix); source chunk
  // XOR-permuted within the 64B row, LDS dest linear (rule #21 both-sides)
  auto SA = [&](int buf, int kk) {
    #pragma unroll
    for (int p2=0;p2<2;++p2) {
      int n = p2*256 + t;
      int row = n >> 2, jj = (n & 3) ^ ((row >> 1) & 3);
      gld16(&A[(size_t)(m0 + row)*1024 + kk + jj*8], &As[buf][n*8]);
    }
  };
  auto SB = [&](int buf, int kk) {
    #pragma unroll
    for (int p2=0;p2<2;++p2) {
      int n = p2*256 + t;
      int row = n >> 2, jj = (n & 3) ^ ((row >> 1) & 3);
      gld16(&Bw[(size_t)(n0 + row)*1024 + kk + jj*8], &Bs[buf][n*8]);
    }
  };

  // prologue: tiles 0,1
  SA(0, 0);  SB(0, 0);
  SA(1, 32); SB(1, 32);

  for (int kt = 0; kt < 32; ++kt) {
    const int cur = kt & 1;
    asm volatile("s_waitcnt vmcnt(4)" ::: "memory");  // tile kt landed; kt+1 in flight
    __builtin_amdgcn_s_barrier();
    __builtin_amdgcn_sched_barrier(0);

    short8 af[4], bf[4];
    #pragma unroll
    for (int i=0;i<4;i++) {
      int rA = wr*64 + i*16 + li;
      int rB = wc*64 + i*16 + li;
      af[i] = *(const short8*)&As[cur][rA*32 + ((c4 ^ ((rA>>1)&3))*8)];
      bf[i] = *(const short8*)&Bs[cur][rB*32 + ((c4 ^ ((rB>>1)&3))*8)];
    }
    __builtin_amdgcn_s_setprio(1);
    #pragma unroll
    for (int i=0;i<4;i++)
      #pragma unroll
      for (int j=0;j<4;j++)
        acc[i][j] = __builtin_amdgcn_mfma_f32_16x16x32_bf16(af[i], bf[j], acc[i][j], 0,0,0);
    __builtin_amdgcn_s_setprio(0);

    __builtin_amdgcn_s_barrier();            // all waves done reading buf[cur]
    __builtin_amdgcn_sched_barrier(0);
    const int kk2 = ((kt + 2) & 31) * 32;    // tail wraps: dummy, never read
    SA(cur, kk2); SB(cur, kk2);
  }

  #pragma unroll
  for (int i=0;i<4;i++) {
    int rbase = m0 + wr*64 + i*16 + c4*4;
    #pragma unroll
    for (int j=0;j<4;j++) {
      int col = n0 + wc*64 + j*16 + li;
      float bv = bias[col];
      if (MODE == 0) {
        int p = col >> 10, h = (col >> 6) & 15, d = col & 63;
        int b = rbase >> 10, s = rbase & 1023;
        if (p == 2) {          // V -> transposed [bh][d][s], 8B packed store
          ushort pk4[4];
          #pragma unroll
          for (int r=0;r<4;r++) pk4[r] = f2b(acc[i][j][r] + bv);
          *(uint2*)&Vtb[((size_t)((b*16+h)*64 + d))*1024 + s] = *(uint2*)pk4;
        } else {
          ushort* dst = (p==0) ? Qb : Kb;
          float sc = (p==0) ? 0.18033688011112042f : 1.0f;   // 0.125*log2(e)
          #pragma unroll
          for (int r=0;r<4;r++)
            dst[(((size_t)(b*16 + h))*1024 + s + r)*64 + d] = f2b((acc[i][j][r] + bv) * sc);
        }
      } else {
        #pragma unroll
        for (int r=0;r<4;r++)
          outF[(size_t)(rbase+r)*1024 + col] = acc[i][j][r] + bv;
      }
    }
  }
}

// ---------------- causal flash attention, paired q-tiles ----------------
// 512 blocks x 256 thr (2/CU, zero tail); wave w of block handles q-tile PAIR
// (p, 31-p), p = (i0&3)*4+w -> 33 tiles of work per wave (balanced) and K/V
// tiles of the shared range loaded ONCE (25% L2 traffic cut). No barriers.
// 32x32x16 MFMAs; swapped QK^T (S[kv][q]) and swapped PV (O[d][q]); softmax
// state per-lane scalar + one shfl_xor(32). Scores in log2 domain.
__global__ __launch_bounds__(256, 2) void attn_kern(
    const ushort* __restrict__ Qb, const ushort* __restrict__ Kb,
    const ushort* __restrict__ Vt, ushort* __restrict__ Ob)
{
  __shared__ __align__(16) ushort Pb[4][32*40];   // per-wave P [q][kv], stride 40
  __shared__ __align__(16) ushort OT[4][32*72];   // per-wave epilogue transpose
  const int t = threadIdx.x, l = t & 63, w = t >> 6;
  const int bid = blockIdx.x;
  const int x = bid & 7, i0 = bid >> 3;           // i0 0..63
  const int bh = x*16 + (i0 >> 2);                // bh clustered per XCD
  const int p  = (i0 & 3)*4 + w;                  // 0..15
  const int qta = p, qtb = 31 - p;

  const int col = l & 31, hi = l >> 5;
  const ushort* Qp = Qb + (size_t)bh*65536;
  const ushort* Kp = Kb + (size_t)bh*65536;
  const ushort* Vp = Vt + (size_t)bh*65536;

  short8 qfa[4], qfb[4];
  #pragma unroll
  for (int m=0;m<4;m++) {
    qfa[m] = *(const short8*)&Qp[(size_t)(qta*32+col)*64 + m*16 + hi*8];
    qfb[m] = *(const short8*)&Qp[(size_t)(qtb*32+col)*64 + m*16 + hi*8];
  }

  f32x16 aA0 = (f32x16)0.0f, aA1 = (f32x16)0.0f;
  f32x16 aB0 = (f32x16)0.0f, aB1 = (f32x16)0.0f;
  float mA = -1e30f, lA = 0.0f, mB = -1e30f, lB = 0.0f;
  ushort* Pw = &Pb[w][0];

  // softmax+PV for one q-tile given its score tile s (S[kv][q] layout)
  auto PROC = [&](f32x16& s, bool diag, float& mR, float& lS,
                  f32x16& o0, f32x16& o1, const short8* vf0, const short8* vf1) {
    if (diag) {
      #pragma unroll
      for (int r=0;r<16;r++) {
        int kvl = (r&3) + ((r>>2)<<3) + 4*hi;
        s[r] = (kvl > col) ? -1e9f : s[r];
      }
    }
    float mx = s[0];
    #pragma unroll
    for (int r=1;r<16;r++) mx = fmaxf(mx, s[r]);
    mx = fmaxf(mx, __shfl_xor(mx, 32));
    if (__any(mx - mR > 8.0f)) {          // T13 defer-max (log2 units)
      float mN = fmaxf(mR, mx);
      float corr = __builtin_amdgcn_exp2f(mR - mN);
      mR = mN; lS *= corr;
      #pragma unroll
      for (int r=0;r<16;r++) { o0[r] *= corr; o1[r] *= corr; }
    }
    float pr[16], rs = 0.0f;
    #pragma unroll
    for (int r=0;r<16;r++) { pr[r] = __builtin_amdgcn_exp2f(s[r] - mR); rs += pr[r]; }
    rs += __shfl_xor(rs, 32);
    lS += rs;
    #pragma unroll
    for (int r2=0;r2<8;r2++) {
      int r = 2*r2;
      int kv = (r&3) + ((r>>2)<<3) + 4*hi;
      *(unsigned*)&Pw[col*40 + kv] = pk2(pr[r], pr[r+1]);
    }
    short8 pb0 = *(const short8*)&Pw[col*40 + hi*8];
    short8 pb1 = *(const short8*)&Pw[col*40 + 16 + hi*8];
    o0 = __builtin_amdgcn_mfma_f32_32x32x16_bf16(vf0[0], pb0, o0, 0,0,0);
    o0 = __builtin_amdgcn_mfma_f32_32x32x16_bf16(vf0[1], pb1, o0, 0,0,0);
    o1 = __builtin_amdgcn_mfma_f32_32x32x16_bf16(vf1[0], pb0, o1, 0,0,0);
    o1 = __builtin_amdgcn_mfma_f32_32x32x16_bf16(vf1[1], pb1, o1, 0,0,0);
  };

  for (int kt = 0; kt <= qtb; ++kt) {
    short8 kf[4], vf0[2], vf1[2];
    #pragma unroll
    for (int m=0;m<4;m++)
      kf[m] = *(const short8*)&Kp[(size_t)(kt*32+col)*64 + m*16 + hi*8];
    #pragma unroll
    for (int m=0;m<2;m++) {
      vf0[m] = *(const short8*)&Vp[(size_t)col*1024      + kt*32 + m*16 + hi*8];
      vf1[m] = *(const short8*)&Vp[(size_t)(32+col)*1024 + kt*32 + m*16 + hi*8];
    }

    f32x16 sB = (f32x16)0.0f;
    #pragma unroll
    for (int m=0;m<4;m++)
      sB = __builtin_amdgcn_mfma_f32_32x32x16_bf16(kf[m], qfb[m], sB, 0, 0, 0);
    PROC(sB, kt == qtb, mB, lB, aB0, aB1, vf0, vf1);

    if (kt <= qta) {
      f32x16 sA = (f32x16)0.0f;
      #pragma unroll
      for (int m=0;m<4;m++)
        sA = __builtin_amdgcn_mfma_f32_32x32x16_bf16(kf[m], qfa[m], sA, 0, 0, 0);
      PROC(sA, kt == qta, mA, lA, aA0, aA1, vf0, vf1);
    }
  }

  // epilogue: O[dv][q] regs -> LDS transpose -> coalesced global store
  const int b = bh >> 4, h = bh & 15;
  auto EPI = [&](int qt, float lS, const f32x16& o0, const f32x16& o1) {
    float inv = 1.0f / lS;
    ushort* o = &OT[w][0];
    #pragma unroll
    for (int r2=0;r2<8;r2++) {
      int r = 2*r2;
      int dv = (r&3) + ((r>>2)<<3) + 4*hi;
      *(unsigned*)&o[col*72 + dv]      = pk2(o0[r]*inv, o0[r+1]*inv);
      *(unsigned*)&o[col*72 + 32 + dv] = pk2(o1[r]*inv, o1[r+1]*inv);
    }
    #pragma unroll
    for (int it=0; it<4; ++it) {
      int q = it*8 + (l>>3), c8 = (l&7)*8;
      uint4 v = *(const uint4*)&o[q*72 + c8];
      int qg = qt*32 + q;
      *(uint4*)&Ob[(size_t)(b*1024+qg)*1024 + h*64 + c8] = v;
    }
  };
  EPI(qta, lA, aA0, aA1);
  EPI(qtb, lB, aB0, aB1);
}

extern "C" void kernel_launch(void* const* d_in, const int* in_sizes, int n_in,
                              void* d_out, int out_size, void* d_ws, size_t ws_size,
                              hipStream_t stream) {
  const float* query = (const float*)d_in[0];
  const float* Wq = (const float*)d_in[4];
  const float* bq = (const float*)d_in[5];
  const float* Wk = (const float*)d_in[6];
  const float* bk = (const float*)d_in[7];
  const float* Wv = (const float*)d_in[8];
  const float* bv = (const float*)d_in[9];
  const float* Wo = (const float*)d_in[10];
  const float* bo = (const float*)d_in[11];

  char* wsb = (char*)d_ws;
  ushort* Xb   = (ushort*)(wsb);                  // 16 MB
  ushort* Wqkv = (ushort*)(wsb + 16777216);       // 6 MB
  float*  Bqkv = (float*) (wsb + 23068672);       // 12 KB
  ushort* Wob  = (ushort*)(wsb + 23080960);       // 2 MB
  ushort* Qb   = (ushort*)(wsb + 25178112);       // 16 MB
  ushort* Kb   = (ushort*)(wsb + 41955328);       // 16 MB
  ushort* Vtb  = (ushort*)(wsb + 58732544);       // 16 MB  [bh][d][s]
  ushort* Ob   = (ushort*)(wsb + 75509760);       // 16 MB

  hipLaunchKernelGGL(pack_x_kern, dim3(4096), dim3(256), 0, stream, query, Xb);
  hipLaunchKernelGGL(pack_w_kern, dim3(1024), dim3(256), 0, stream,
                     Wq, Wk, Wv, bq, bk, bv, Wo, Wqkv, Bqkv, Wob);
  hipLaunchKernelGGL(gemm128_kern<0>, dim3(1536), dim3(256), 0, stream,
                     Xb, Wqkv, Bqkv, Qb, Kb, Vtb, (float*)nullptr);
  hipLaunchKernelGGL(attn_kern, dim3(512), dim3(256), 0, stream, Qb, Kb, Vtb, Ob);
  hipLaunchKernelGGL(gemm128_kern<1>, dim3(512), dim3(256), 0, stream,
                     Ob, Wob, bo, (ushort*)nullptr, (ushort*)nullptr, (ushort*)nullptr,
                     (float*)d_out);
}

// Round 11
// 164.645 us; speedup vs baseline: 1.1198x; 1.0191x over previous
//
#include <hip/hip_runtime.h>
#include <hip/hip_bf16.h>

#define B_ 8
#define S_ 1024
#define U_ 1024
#define H_ 16
#define DK_ 64

typedef __attribute__((ext_vector_type(8))) short short8;
typedef __attribute__((ext_vector_type(4))) float f32x4;
typedef __attribute__((ext_vector_type(16))) float f32x16;

__device__ inline ushort f2b(float x) {
  union { float f; unsigned u; } v; v.f = x;
  unsigned r = (v.u + 0x7FFFu + ((v.u >> 16) & 1u)) >> 16;
  return (ushort)r;
}
__device__ inline unsigned pk2(float lo, float hi) {
  return (unsigned)f2b(lo) | ((unsigned)f2b(hi) << 16);
}

__device__ inline void gld16(const ushort* g, ushort* l) {
  __builtin_amdgcn_global_load_lds((__attribute__((address_space(1))) void*)(g),
                                   (__attribute__((address_space(3))) void*)(l),
                                   16, 0, 0);
}

// ---------------- pack query fp32 -> bf16 ----------------
__global__ __launch_bounds__(256) void pack_x_kern(const float* __restrict__ X,
                                                   ushort* __restrict__ Xb) {
  int idx = blockIdx.x * 256 + threadIdx.x;
  const float4* src = (const float4*)X + (size_t)idx * 2;
  float4 a = src[0], b = src[1];
  ushort r[8];
  r[0]=f2b(a.x); r[1]=f2b(a.y); r[2]=f2b(a.z); r[3]=f2b(a.w);
  r[4]=f2b(b.x); r[5]=f2b(b.y); r[6]=f2b(b.z); r[7]=f2b(b.w);
  *(uint4*)(Xb + (size_t)idx*8) = *(uint4*)r;
}

// ---------------- pack weights (transpose to [n][k], bf16) ----------------
__global__ __launch_bounds__(256) void pack_w_kern(
    const float* __restrict__ Wq, const float* __restrict__ Wk, const float* __restrict__ Wv,
    const float* __restrict__ bq, const float* __restrict__ bk, const float* __restrict__ bv,
    const float* __restrict__ Wo,
    ushort* __restrict__ Wqkv, float* __restrict__ Bqkv, ushort* __restrict__ Wob)
{
  __shared__ ushort tile[64*65];
  const int t = threadIdx.x;
  const int bid = blockIdx.x;
  if (bid < 768) {
    int p = bid >> 8, rem = bid & 255;
    int h = rem >> 4, kc = rem & 15, k0 = kc*64;
    const float* Wsrc = (p==0) ? Wq : ((p==1) ? Wk : Wv);
    #pragma unroll
    for (int i = 0; i < 16; ++i) {
      int e = t + i*256;
      int r = e >> 6, d = e & 63;
      tile[d*65 + r] = f2b(Wsrc[h*65536 + (k0+r)*64 + d]);
    }
    __syncthreads();
    #pragma unroll
    for (int i = 0; i < 16; ++i) {
      int e = t + i*256;
      int d = e >> 6, r = e & 63;
      Wqkv[(size_t)(p*1024 + h*64 + d)*1024 + k0 + r] = tile[d*65 + r];
    }
    if (kc == 0 && t < 64) {
      const float* bsrc = (p==0) ? bq : ((p==1) ? bk : bv);
      Bqkv[p*1024 + h*64 + t] = bsrc[h*64 + t];
    }
  } else {
    int b2 = bid - 768;
    int nc = b2 >> 4, kc = b2 & 15;
    int n0 = nc*64, k0 = kc*64;
    #pragma unroll
    for (int i = 0; i < 16; ++i) {
      int e = t + i*256;
      int r = e >> 6, d = e & 63;
      tile[d*65 + r] = f2b(Wo[(size_t)(k0+r)*1024 + n0 + d]);
    }
    __syncthreads();
    #pragma unroll
    for (int i = 0; i < 16; ++i) {
      int e = t + i*256;
      int d = e >> 6, r = e & 63;
      Wob[(size_t)(n0+d)*1024 + k0 + r] = tile[d*65 + r];
    }
  }
}

// ---- GEMM: 128x128x64, dbuf + counted vmcnt, 2 blocks/CU (round-9 best) ----
// 256 thr = 4 waves (2M x 2N). LDS: 2 dbuf x (A[128][64] + B[128][64]) = 64 KB
// -> 2 blocks/CU. Per K-tile: {ds_read 16 frags, setprio1, 32 MFMA, setprio0,
// s_barrier, stage tile t+2 (8 gld_lds), vmcnt(8) [counted: waits tile t+1,
// leaves t+2 in flight], s_barrier}. Never vmcnt(0) in loop. XOR-chunk swizzle
// both-sides (0-conflict proven).
// MODE 0: N=3072 QKV proj -> Q (x0.125*log2e) [bh][s][d], K [bh][s][d],
//         V transposed [bh][d][s].  MODE 1: N=1024 out proj -> fp32.
template<int MODE>
__global__ __launch_bounds__(256, 2) void gemm128_kern(
    const ushort* __restrict__ A,
    const ushort* __restrict__ Bw,
    const float* __restrict__ bias,
    ushort* __restrict__ Qb, ushort* __restrict__ Kb, ushort* __restrict__ Vtb,
    float* __restrict__ outF)
{
  __shared__ __align__(16) ushort As[2][8192];   // [dbuf][(row 0..127)*64+col]
  __shared__ __align__(16) ushort Bs[2][8192];

  const int t = threadIdx.x;
  const int l = t & 63, w = t >> 6;
  const int wr = w >> 1, wc = w & 1;
  const int li = l & 15, c4 = l >> 4;

  // raster: m-supertiles of 8 x all-n, bijective XCD chunking
  int m0, n0;
  if (MODE==0) {      // 1536 blocks = 64m x 24n; chunk 192 = 8m x 24n
    int swz = (blockIdx.x & 7) * 192 + (blockIdx.x >> 3);
    int ms = swz / 192, rem = swz % 192;
    m0 = (ms*8 + (rem & 7)) * 128;  n0 = (rem >> 3) * 128;
  } else {            // 512 blocks = 64m x 8n; chunk 64 = 8m x 8n
    int swz = (blockIdx.x & 7) * 64 + (blockIdx.x >> 3);
    int ms = swz / 64, rem = swz % 64;
    m0 = (ms*8 + (rem & 7)) * 128;  n0 = (rem >> 3) * 128;
  }

  f32x4 acc[4][4];
  #pragma unroll
  for (int i=0;i<4;i++)
    #pragma unroll
    for (int j=0;j<4;j++) acc[i][j] = (f32x4)0.0f;

  // stage one 128x64 tile (1024 16B-chunks, 4/thread); source chunk
  // XOR-permuted within the 128B row, LDS dest linear (rule #21 both-sides)
  auto SA = [&](int buf, int kk) {
    #pragma unroll
    for (int p=0;p<4;++p) {
      int n = p*256 + t;
      int row = n >> 3, jj = (n & 7) ^ (row & 7);
      gld16(&A[(size_t)(m0 + row)*1024 + kk + jj*8], &As[buf][n*8]);
    }
  };
  auto SB = [&](int buf, int kk) {
    #pragma unroll
    for (int p=0;p<4;++p) {
      int n = p*256 + t;
      int row = n >> 3, jj = (n & 7) ^ (row & 7);
      gld16(&Bw[(size_t)(n0 + row)*1024 + kk + jj*8], &Bs[buf][n*8]);
    }
  };

  // prologue: tiles 0,1
  SA(0, 0);  SB(0, 0);
  SA(1, 64); SB(1, 64);
  asm volatile("s_waitcnt vmcnt(8)" ::: "memory");   // tile 0 landed
  __builtin_amdgcn_s_barrier();
  __builtin_amdgcn_sched_barrier(0);

  for (int kt = 0; kt < 16; ++kt) {
    const int cur = kt & 1;
    short8 af[4][2], bf[4][2];
    #pragma unroll
    for (int i=0;i<4;i++) {
      int rA = wr*64 + i*16 + li;
      int rB = wc*64 + i*16 + li;
      #pragma unroll
      for (int ks=0;ks<2;ks++) {
        af[i][ks] = *(const short8*)&As[cur][rA*64 + (((ks*4+c4)^(li&7))*8)];
        bf[i][ks] = *(const short8*)&Bs[cur][rB*64 + (((ks*4+c4)^(li&7))*8)];
      }
    }
    __builtin_amdgcn_s_setprio(1);
    #pragma unroll
    for (int i=0;i<4;i++)
      #pragma unroll
      for (int j=0;j<4;j++)
        #pragma unroll
        for (int ks=0;ks<2;ks++)
          acc[i][j] = __builtin_amdgcn_mfma_f32_16x16x32_bf16(af[i][ks], bf[j][ks], acc[i][j], 0,0,0);
    __builtin_amdgcn_s_setprio(0);

    __builtin_amdgcn_s_barrier();            // all waves done reading buf[cur]
    __builtin_amdgcn_sched_barrier(0);
    const int kk2 = ((kt + 2) & 15) * 64;    // tail wraps: dummy, never read
    SA(cur, kk2); SB(cur, kk2);
    asm volatile("s_waitcnt vmcnt(8)" ::: "memory");  // tile kt+1 landed; t+2 in flight
    __builtin_amdgcn_s_barrier();
    __builtin_amdgcn_sched_barrier(0);
  }

  #pragma unroll
  for (int i=0;i<4;i++) {
    int rbase = m0 + wr*64 + i*16 + c4*4;
    #pragma unroll
    for (int j=0;j<4;j++) {
      int col = n0 + wc*64 + j*16 + li;
      float bv = bias[col];
      if (MODE == 0) {
        int p = col >> 10, h = (col >> 6) & 15, d = col & 63;
        int b = rbase >> 10, s = rbase & 1023;
        if (p == 2) {          // V -> transposed [bh][d][s], 8B packed store
          ushort pk4[4];
          #pragma unroll
          for (int r=0;r<4;r++) pk4[r] = f2b(acc[i][j][r] + bv);
          *(uint2*)&Vtb[((size_t)((b*16+h)*64 + d))*1024 + s] = *(uint2*)pk4;
        } else {
          ushort* dst = (p==0) ? Qb : Kb;
          float sc = (p==0) ? 0.18033688011112042f : 1.0f;   // 0.125*log2(e)
          #pragma unroll
          for (int r=0;r<4;r++)
            dst[(((size_t)(b*16 + h))*1024 + s + r)*64 + d] = f2b((acc[i][j][r] + bv) * sc);
        }
      } else {
        #pragma unroll
        for (int r=0;r<4;r++)
          outF[(size_t)(rbase+r)*1024 + col] = acc[i][j][r] + bv;
      }
    }
  }
}

// ---------------- causal flash attention, paired q-tiles + T14 prefetch -----
// 512 blocks x 256 thr (2/CU, zero tail); wave w handles q-tile PAIR (p, 31-p),
// p=(i0&3)*4+w. K/V for kt+1 prefetched into registers BEFORE processing kt so
// L2 latency hides under softmax/PV work; the two independent QK^T chains are
// issued back-to-back to fill MFMA->softmax latency. No barriers. Swapped
// QK^T (S[kv][q]) and swapped PV (O[d][q]); per-lane softmax state + one
// shfl_xor(32). Scores in log2 domain.
__global__ __launch_bounds__(256, 2) void attn_kern(
    const ushort* __restrict__ Qb, const ushort* __restrict__ Kb,
    const ushort* __restrict__ Vt, ushort* __restrict__ Ob)
{
  __shared__ __align__(16) ushort Pb[4][32*40];   // per-wave P [q][kv], stride 40
  __shared__ __align__(16) ushort OT[4][32*72];   // per-wave epilogue transpose
  const int t = threadIdx.x, l = t & 63, w = t >> 6;
  const int bid = blockIdx.x;
  const int x = bid & 7, i0 = bid >> 3;           // i0 0..63
  const int bh = x*16 + (i0 >> 2);                // bh clustered per XCD
  const int p  = (i0 & 3)*4 + w;                  // 0..15
  const int qta = p, qtb = 31 - p;

  const int col = l & 31, hi = l >> 5;
  const ushort* Qp = Qb + (size_t)bh*65536;
  const ushort* Kp = Kb + (size_t)bh*65536;
  const ushort* Vp = Vt + (size_t)bh*65536;

  short8 qfa[4], qfb[4];
  #pragma unroll
  for (int m=0;m<4;m++) {
    qfa[m] = *(const short8*)&Qp[(size_t)(qta*32+col)*64 + m*16 + hi*8];
    qfb[m] = *(const short8*)&Qp[(size_t)(qtb*32+col)*64 + m*16 + hi*8];
  }

  f32x16 aA0 = (f32x16)0.0f, aA1 = (f32x16)0.0f;
  f32x16 aB0 = (f32x16)0.0f, aB1 = (f32x16)0.0f;
  float mA = -1e30f, lA = 0.0f, mB = -1e30f, lB = 0.0f;
  ushort* Pw = &Pb[w][0];

  auto PROC = [&](f32x16& s, bool diag, float& mR, float& lS,
                  f32x16& o0, f32x16& o1, const short8* vf0, const short8* vf1) {
    if (diag) {
      #pragma unroll
      for (int r=0;r<16;r++) {
        int kvl = (r&3) + ((r>>2)<<3) + 4*hi;
        s[r] = (kvl > col) ? -1e9f : s[r];
      }
    }
    float mx = s[0];
    #pragma unroll
    for (int r=1;r<16;r++) mx = fmaxf(mx, s[r]);
    mx = fmaxf(mx, __shfl_xor(mx, 32));
    if (__any(mx - mR > 8.0f)) {          // T13 defer-max (log2 units)
      float mN = fmaxf(mR, mx);
      float corr = __builtin_amdgcn_exp2f(mR - mN);
      mR = mN; lS *= corr;
      #pragma unroll
      for (int r=0;r<16;r++) { o0[r] *= corr; o1[r] *= corr; }
    }
    float pr[16], rs = 0.0f;
    #pragma unroll
    for (int r=0;r<16;r++) { pr[r] = __builtin_amdgcn_exp2f(s[r] - mR); rs += pr[r]; }
    rs += __shfl_xor(rs, 32);
    lS += rs;
    #pragma unroll
    for (int r2=0;r2<8;r2++) {
      int r = 2*r2;
      int kv = (r&3) + ((r>>2)<<3) + 4*hi;
      *(unsigned*)&Pw[col*40 + kv] = pk2(pr[r], pr[r+1]);
    }
    short8 pb0 = *(const short8*)&Pw[col*40 + hi*8];
    short8 pb1 = *(const short8*)&Pw[col*40 + 16 + hi*8];
    o0 = __builtin_amdgcn_mfma_f32_32x32x16_bf16(vf0[0], pb0, o0, 0,0,0);
    o0 = __builtin_amdgcn_mfma_f32_32x32x16_bf16(vf0[1], pb1, o0, 0,0,0);
    o1 = __builtin_amdgcn_mfma_f32_32x32x16_bf16(vf1[0], pb0, o1, 0,0,0);
    o1 = __builtin_amdgcn_mfma_f32_32x32x16_bf16(vf1[1], pb1, o1, 0,0,0);
  };

  auto LOADKV = [&](int kt, short8* kf_, short8* v0_, short8* v1_) {
    #pragma unroll
    for (int m=0;m<4;m++)
      kf_[m] = *(const short8*)&Kp[(size_t)(kt*32+col)*64 + m*16 + hi*8];
    #pragma unroll
    for (int m=0;m<2;m++) {
      v0_[m] = *(const short8*)&Vp[(size_t)col*1024      + kt*32 + m*16 + hi*8];
      v1_[m] = *(const short8*)&Vp[(size_t)(32+col)*1024 + kt*32 + m*16 + hi*8];
    }
  };

  short8 kf[4], vf0[2], vf1[2];
  LOADKV(0, kf, vf0, vf1);

  for (int kt = 0; kt <= qtb; ++kt) {
    // T14: prefetch next tile's K/V into registers (L2 latency hides under
    // this iteration's softmax/PV work)
    short8 kf2[4], v02[2], v12[2];
    const int ktn = (kt + 1 <= qtb) ? kt + 1 : qtb;
    LOADKV(ktn, kf2, v02, v12);

    const bool doA = (kt <= qta);
    f32x16 sB = (f32x16)0.0f, sA = (f32x16)0.0f;
    #pragma unroll
    for (int m=0;m<4;m++)
      sB = __builtin_amdgcn_mfma_f32_32x32x16_bf16(kf[m], qfb[m], sB, 0, 0, 0);
    if (doA) {
      #pragma unroll
      for (int m=0;m<4;m++)
        sA = __builtin_amdgcn_mfma_f32_32x32x16_bf16(kf[m], qfa[m], sA, 0, 0, 0);
    }

    PROC(sB, kt == qtb, mB, lB, aB0, aB1, vf0, vf1);
    if (doA) PROC(sA, kt == qta, mA, lA, aA0, aA1, vf0, vf1);

    #pragma unroll
    for (int m=0;m<4;m++) kf[m] = kf2[m];
    #pragma unroll
    for (int m=0;m<2;m++) { vf0[m] = v02[m]; vf1[m] = v12[m]; }
  }

  // epilogue: O[dv][q] regs -> LDS transpose -> coalesced global store
  const int b = bh >> 4, h = bh & 15;
  auto EPI = [&](int qt, float lS, const f32x16& o0, const f32x16& o1) {
    float inv = 1.0f / lS;
    ushort* o = &OT[w][0];
    #pragma unroll
    for (int r2=0;r2<8;r2++) {
      int r = 2*r2;
      int dv = (r&3) + ((r>>2)<<3) + 4*hi;
      *(unsigned*)&o[col*72 + dv]      = pk2(o0[r]*inv, o0[r+1]*inv);
      *(unsigned*)&o[col*72 + 32 + dv] = pk2(o1[r]*inv, o1[r+1]*inv);
    }
    #pragma unroll
    for (int it=0; it<4; ++it) {
      int q = it*8 + (l>>3), c8 = (l&7)*8;
      uint4 v = *(const uint4*)&o[q*72 + c8];
      int qg = qt*32 + q;
      *(uint4*)&Ob[(size_t)(b*1024+qg)*1024 + h*64 + c8] = v;
    }
  };
  EPI(qta, lA, aA0, aA1);
  EPI(qtb, lB, aB0, aB1);
}

extern "C" void kernel_launch(void* const* d_in, const int* in_sizes, int n_in,
                              void* d_out, int out_size, void* d_ws, size_t ws_size,
                              hipStream_t stream) {
  const float* query = (const float*)d_in[0];
  const float* Wq = (const float*)d_in[4];
  const float* bq = (const float*)d_in[5];
  const float* Wk = (const float*)d_in[6];
  const float* bk = (const float*)d_in[7];
  const float* Wv = (const float*)d_in[8];
  const float* bv = (const float*)d_in[9];
  const float* Wo = (const float*)d_in[10];
  const float* bo = (const float*)d_in[11];

  char* wsb = (char*)d_ws;
  ushort* Xb   = (ushort*)(wsb);                  // 16 MB
  ushort* Wqkv = (ushort*)(wsb + 16777216);       // 6 MB
  float*  Bqkv = (float*) (wsb + 23068672);       // 12 KB
  ushort* Wob  = (ushort*)(wsb + 23080960);       // 2 MB
  ushort* Qb   = (ushort*)(wsb + 25178112);       // 16 MB
  ushort* Kb   = (ushort*)(wsb + 41955328);       // 16 MB
  ushort* Vtb  = (ushort*)(wsb + 58732544);       // 16 MB  [bh][d][s]
  ushort* Ob   = (ushort*)(wsb + 75509760);       // 16 MB

  hipLaunchKernelGGL(pack_x_kern, dim3(4096), dim3(256), 0, stream, query, Xb);
  hipLaunchKernelGGL(pack_w_kern, dim3(1024), dim3(256), 0, stream,
                     Wq, Wk, Wv, bq, bk, bv, Wo, Wqkv, Bqkv, Wob);
  hipLaunchKernelGGL(gemm128_kern<0>, dim3(1536), dim3(256), 0, stream,
                     Xb, Wqkv, Bqkv, Qb, Kb, Vtb, (float*)nullptr);
  hipLaunchKernelGGL(attn_kern, dim3(512), dim3(256), 0, stream, Qb, Kb, Vtb, Ob);
  hipLaunchKernelGGL(gemm128_kern<1>, dim3(512), dim3(256), 0, stream,
                     Ob, Wob, bo, (ushort*)nullptr, (ushort*)nullptr, (ushort*)nullptr,
                     (float*)d_out);
}

// Round 12
// 164.377 us; speedup vs baseline: 1.1216x; 1.0016x over previous
//
#include <hip/hip_runtime.h>
#include <hip/hip_bf16.h>

#define B_ 8
#define S_ 1024
#define U_ 1024
#define H_ 16
#define DK_ 64

typedef __attribute__((ext_vector_type(8))) short short8;
typedef __attribute__((ext_vector_type(4))) float f32x4;
typedef __attribute__((ext_vector_type(16))) float f32x16;

__device__ inline ushort f2b(float x) {
  union { float f; unsigned u; } v; v.f = x;
  unsigned r = (v.u + 0x7FFFu + ((v.u >> 16) & 1u)) >> 16;
  return (ushort)r;
}
__device__ inline unsigned pk2(float lo, float hi) {
  return (unsigned)f2b(lo) | ((unsigned)f2b(hi) << 16);
}

__device__ inline void gld16(const ushort* g, ushort* l) {
  __builtin_amdgcn_global_load_lds((__attribute__((address_space(1))) void*)(g),
                                   (__attribute__((address_space(3))) void*)(l),
                                   16, 0, 0);
}

// ------------- fused pack: query fp32->bf16 + weight transpose ---------------
// blocks 0..4095: pack X (8 floats/thread). blocks 4096..5119: pack weights.
__global__ __launch_bounds__(256) void pack_all_kern(
    const float* __restrict__ X, ushort* __restrict__ Xb,
    const float* __restrict__ Wq, const float* __restrict__ Wk, const float* __restrict__ Wv,
    const float* __restrict__ bq, const float* __restrict__ bk, const float* __restrict__ bv,
    const float* __restrict__ Wo,
    ushort* __restrict__ Wqkv, float* __restrict__ Bqkv, ushort* __restrict__ Wob)
{
  __shared__ ushort tile[64*65];
  const int t = threadIdx.x;
  if (blockIdx.x < 4096) {
    int idx = blockIdx.x * 256 + t;
    const float4* src = (const float4*)X + (size_t)idx * 2;
    float4 a = src[0], b = src[1];
    ushort r[8];
    r[0]=f2b(a.x); r[1]=f2b(a.y); r[2]=f2b(a.z); r[3]=f2b(a.w);
    r[4]=f2b(b.x); r[5]=f2b(b.y); r[6]=f2b(b.z); r[7]=f2b(b.w);
    *(uint4*)(Xb + (size_t)idx*8) = *(uint4*)r;
    return;
  }
  const int bid = blockIdx.x - 4096;
  if (bid < 768) {
    int p = bid >> 8, rem = bid & 255;
    int h = rem >> 4, kc = rem & 15, k0 = kc*64;
    const float* Wsrc = (p==0) ? Wq : ((p==1) ? Wk : Wv);
    #pragma unroll
    for (int i = 0; i < 16; ++i) {
      int e = t + i*256;
      int r = e >> 6, d = e & 63;
      tile[d*65 + r] = f2b(Wsrc[h*65536 + (k0+r)*64 + d]);
    }
    __syncthreads();
    #pragma unroll
    for (int i = 0; i < 16; ++i) {
      int e = t + i*256;
      int d = e >> 6, r = e & 63;
      Wqkv[(size_t)(p*1024 + h*64 + d)*1024 + k0 + r] = tile[d*65 + r];
    }
    if (kc == 0 && t < 64) {
      const float* bsrc = (p==0) ? bq : ((p==1) ? bk : bv);
      Bqkv[p*1024 + h*64 + t] = bsrc[h*64 + t];
    }
  } else {
    int b2 = bid - 768;
    int nc = b2 >> 4, kc = b2 & 15;
    int n0 = nc*64, k0 = kc*64;
    #pragma unroll
    for (int i = 0; i < 16; ++i) {
      int e = t + i*256;
      int r = e >> 6, d = e & 63;
      tile[d*65 + r] = f2b(Wo[(size_t)(k0+r)*1024 + n0 + d]);
    }
    __syncthreads();
    #pragma unroll
    for (int i = 0; i < 16; ++i) {
      int e = t + i*256;
      int d = e >> 6, r = e & 63;
      Wob[(size_t)(n0+d)*1024 + k0 + r] = tile[d*65 + r];
    }
  }
}

// ---- GEMM: 128x128x32, TRIPLE buffer, 3 blocks/CU, counted vmcnt -----------
// 256 thr = 4 waves (2M x 2N). LDS: 3 buf x (A[128][32]+B[128][32]) = 48 KB ->
// 3 blocks/CU. Per K-step: vmcnt(4) [counted: kt landed, kt+1 in flight] ->
// s_barrier -> ds_read 8 frags -> s_barrier -> stage kt+2 into slot (kt+2)%3
// [safe: slot last read at step kt-1, all waves past that step's barrier] ->
// 16 MFMA. Both barriers BEFORE the MFMA cluster: MFMA overlaps stage issue +
// flight; 3 co-resident blocks fill stalls. Never vmcnt(0) in loop. XOR-chunk
// swizzle (slot = chunk ^ ((row>>1)&3)) on staging source + ds_read (rule #21).
// MODE 0: N=3072 QKV proj -> Q (x0.125*log2e) [bh][s][d], K [bh][s][d],
//         V transposed [bh][d][s].  MODE 1: N=1024 out proj -> fp32.
template<int MODE>
__global__ __launch_bounds__(256, 3) void gemm128_kern(
    const ushort* __restrict__ A,
    const ushort* __restrict__ Bw,
    const float* __restrict__ bias,
    ushort* __restrict__ Qb, ushort* __restrict__ Kb, ushort* __restrict__ Vtb,
    float* __restrict__ outF)
{
  __shared__ __align__(16) ushort As[3][4096];   // [buf][(row 0..127)*32+col]
  __shared__ __align__(16) ushort Bs[3][4096];

  const int t = threadIdx.x;
  const int l = t & 63, w = t >> 6;
  const int wr = w >> 1, wc = w & 1;
  const int li = l & 15, c4 = l >> 4;

  // raster: m-supertiles of 8 x all-n, bijective XCD chunking
  int m0, n0;
  if (MODE==0) {      // 1536 blocks = 64m x 24n; chunk 192 = 8m x 24n
    int swz = (blockIdx.x & 7) * 192 + (blockIdx.x >> 3);
    int ms = swz / 192, rem = swz % 192;
    m0 = (ms*8 + (rem & 7)) * 128;  n0 = (rem >> 3) * 128;
  } else {            // 512 blocks = 64m x 8n; chunk 64 = 8m x 8n
    int swz = (blockIdx.x & 7) * 64 + (blockIdx.x >> 3);
    int ms = swz / 64, rem = swz % 64;
    m0 = (ms*8 + (rem & 7)) * 128;  n0 = (rem >> 3) * 128;
  }

  f32x4 acc[4][4];
  #pragma unroll
  for (int i=0;i<4;i++)
    #pragma unroll
    for (int j=0;j<4;j++) acc[i][j] = (f32x4)0.0f;

  // stage one 128x32 tile (512 16B-chunks, 2/thread per matrix); source chunk
  // XOR-permuted within the 64B row, LDS dest linear (rule #21 both-sides)
  auto SA = [&](int buf, int kk) {
    #pragma unroll
    for (int p2=0;p2<2;++p2) {
      int n = p2*256 + t;
      int row = n >> 2, jj = (n & 3) ^ ((row >> 1) & 3);
      gld16(&A[(size_t)(m0 + row)*1024 + kk + jj*8], &As[buf][n*8]);
    }
  };
  auto SB = [&](int buf, int kk) {
    #pragma unroll
    for (int p2=0;p2<2;++p2) {
      int n = p2*256 + t;
      int row = n >> 2, jj = (n & 3) ^ ((row >> 1) & 3);
      gld16(&Bw[(size_t)(n0 + row)*1024 + kk + jj*8], &Bs[buf][n*8]);
    }
  };

  // prologue: tiles 0,1 into buffers 0,1
  SA(0, 0);  SB(0, 0);
  SA(1, 32); SB(1, 32);

  for (int kt = 0; kt < 32; ++kt) {
    const int cur = kt % 3;
    asm volatile("s_waitcnt vmcnt(4)" ::: "memory");  // tile kt landed; kt+1 in flight
    __builtin_amdgcn_s_barrier();
    __builtin_amdgcn_sched_barrier(0);

    short8 af[4], bf[4];
    #pragma unroll
    for (int i=0;i<4;i++) {
      int rA = wr*64 + i*16 + li;
      int rB = wc*64 + i*16 + li;
      af[i] = *(const short8*)&As[cur][rA*32 + ((c4 ^ ((rA>>1)&3))*8)];
      bf[i] = *(const short8*)&Bs[cur][rB*32 + ((c4 ^ ((rB>>1)&3))*8)];
    }
    __builtin_amdgcn_s_barrier();            // all waves done reading slot (kt+2)%3
    __builtin_amdgcn_sched_barrier(0);       //   (they read it at step kt-1)
    const int nb = (kt + 2) % 3;
    const int kk2 = ((kt + 2) & 31) * 32;    // tail wraps: dummy, never read
    SA(nb, kk2); SB(nb, kk2);

    __builtin_amdgcn_s_setprio(1);
    #pragma unroll
    for (int i=0;i<4;i++)
      #pragma unroll
      for (int j=0;j<4;j++)
        acc[i][j] = __builtin_amdgcn_mfma_f32_16x16x32_bf16(af[i], bf[j], acc[i][j], 0,0,0);
    __builtin_amdgcn_s_setprio(0);
  }

  #pragma unroll
  for (int i=0;i<4;i++) {
    int rbase = m0 + wr*64 + i*16 + c4*4;
    #pragma unroll
    for (int j=0;j<4;j++) {
      int col = n0 + wc*64 + j*16 + li;
      float bv = bias[col];
      if (MODE == 0) {
        int p = col >> 10, h = (col >> 6) & 15, d = col & 63;
        int b = rbase >> 10, s = rbase & 1023;
        if (p == 2) {          // V -> transposed [bh][d][s], 8B packed store
          ushort pk4[4];
          #pragma unroll
          for (int r=0;r<4;r++) pk4[r] = f2b(acc[i][j][r] + bv);
          *(uint2*)&Vtb[((size_t)((b*16+h)*64 + d))*1024 + s] = *(uint2*)pk4;
        } else {
          ushort* dst = (p==0) ? Qb : Kb;
          float sc = (p==0) ? 0.18033688011112042f : 1.0f;   // 0.125*log2(e)
          #pragma unroll
          for (int r=0;r<4;r++)
            dst[(((size_t)(b*16 + h))*1024 + s + r)*64 + d] = f2b((acc[i][j][r] + bv) * sc);
        }
      } else {
        #pragma unroll
        for (int r=0;r<4;r++)
          outF[(size_t)(rbase+r)*1024 + col] = acc[i][j][r] + bv;
      }
    }
  }
}

// ---------------- causal flash attention, paired q-tiles + T14 prefetch -----
// 512 blocks x 256 thr (2/CU, zero tail); wave w handles q-tile PAIR (p, 31-p),
// p=(i0&3)*4+w. K/V for kt+1 prefetched into registers BEFORE processing kt so
// L2 latency hides under softmax/PV work. No barriers. Swapped QK^T (S[kv][q])
// and swapped PV (O[d][q]); per-lane softmax state + one shfl_xor(32).
// Scores in log2 domain.
__global__ __launch_bounds__(256, 2) void attn_kern(
    const ushort* __restrict__ Qb, const ushort* __restrict__ Kb,
    const ushort* __restrict__ Vt, ushort* __restrict__ Ob)
{
  __shared__ __align__(16) ushort Pb[4][32*40];   // per-wave P [q][kv], stride 40
  __shared__ __align__(16) ushort OT[4][32*72];   // per-wave epilogue transpose
  const int t = threadIdx.x, l = t & 63, w = t >> 6;
  const int bid = blockIdx.x;
  const int x = bid & 7, i0 = bid >> 3;           // i0 0..63
  const int bh = x*16 + (i0 >> 2);                // bh clustered per XCD
  const int p  = (i0 & 3)*4 + w;                  // 0..15
  const int qta = p, qtb = 31 - p;

  const int col = l & 31, hi = l >> 5;
  const ushort* Qp = Qb + (size_t)bh*65536;
  const ushort* Kp = Kb + (size_t)bh*65536;
  const ushort* Vp = Vt + (size_t)bh*65536;

  short8 qfa[4], qfb[4];
  #pragma unroll
  for (int m=0;m<4;m++) {
    qfa[m] = *(const short8*)&Qp[(size_t)(qta*32+col)*64 + m*16 + hi*8];
    qfb[m] = *(const short8*)&Qp[(size_t)(qtb*32+col)*64 + m*16 + hi*8];
  }

  f32x16 aA0 = (f32x16)0.0f, aA1 = (f32x16)0.0f;
  f32x16 aB0 = (f32x16)0.0f, aB1 = (f32x16)0.0f;
  float mA = -1e30f, lA = 0.0f, mB = -1e30f, lB = 0.0f;
  ushort* Pw = &Pb[w][0];

  auto PROC = [&](f32x16& s, bool diag, float& mR, float& lS,
                  f32x16& o0, f32x16& o1, const short8* vf0, const short8* vf1) {
    if (diag) {
      #pragma unroll
      for (int r=0;r<16;r++) {
        int kvl = (r&3) + ((r>>2)<<3) + 4*hi;
        s[r] = (kvl > col) ? -1e9f : s[r];
      }
    }
    float mx = s[0];
    #pragma unroll
    for (int r=1;r<16;r++) mx = fmaxf(mx, s[r]);
    mx = fmaxf(mx, __shfl_xor(mx, 32));
    if (__any(mx - mR > 8.0f)) {          // T13 defer-max (log2 units)
      float mN = fmaxf(mR, mx);
      float corr = __builtin_amdgcn_exp2f(mR - mN);
      mR = mN; lS *= corr;
      #pragma unroll
      for (int r=0;r<16;r++) { o0[r] *= corr; o1[r] *= corr; }
    }
    float pr[16], rs = 0.0f;
    #pragma unroll
    for (int r=0;r<16;r++) { pr[r] = __builtin_amdgcn_exp2f(s[r] - mR); rs += pr[r]; }
    rs += __shfl_xor(rs, 32);
    lS += rs;
    #pragma unroll
    for (int r2=0;r2<8;r2++) {
      int r = 2*r2;
      int kv = (r&3) + ((r>>2)<<3) + 4*hi;
      *(unsigned*)&Pw[col*40 + kv] = pk2(pr[r], pr[r+1]);
    }
    short8 pb0 = *(const short8*)&Pw[col*40 + hi*8];
    short8 pb1 = *(const short8*)&Pw[col*40 + 16 + hi*8];
    o0 = __builtin_amdgcn_mfma_f32_32x32x16_bf16(vf0[0], pb0, o0, 0,0,0);
    o0 = __builtin_amdgcn_mfma_f32_32x32x16_bf16(vf0[1], pb1, o0, 0,0,0);
    o1 = __builtin_amdgcn_mfma_f32_32x32x16_bf16(vf1[0], pb0, o1, 0,0,0);
    o1 = __builtin_amdgcn_mfma_f32_32x32x16_bf16(vf1[1], pb1, o1, 0,0,0);
  };

  auto LOADKV = [&](int kt, short8* kf_, short8* v0_, short8* v1_) {
    #pragma unroll
    for (int m=0;m<4;m++)
      kf_[m] = *(const short8*)&Kp[(size_t)(kt*32+col)*64 + m*16 + hi*8];
    #pragma unroll
    for (int m=0;m<2;m++) {
      v0_[m] = *(const short8*)&Vp[(size_t)col*1024      + kt*32 + m*16 + hi*8];
      v1_[m] = *(const short8*)&Vp[(size_t)(32+col)*1024 + kt*32 + m*16 + hi*8];
    }
  };

  short8 kf[4], vf0[2], vf1[2];
  LOADKV(0, kf, vf0, vf1);

  for (int kt = 0; kt <= qtb; ++kt) {
    short8 kf2[4], v02[2], v12[2];
    const int ktn = (kt + 1 <= qtb) ? kt + 1 : qtb;
    LOADKV(ktn, kf2, v02, v12);

    const bool doA = (kt <= qta);
    f32x16 sB = (f32x16)0.0f, sA = (f32x16)0.0f;
    #pragma unroll
    for (int m=0;m<4;m++)
      sB = __builtin_amdgcn_mfma_f32_32x32x16_bf16(kf[m], qfb[m], sB, 0, 0, 0);
    if (doA) {
      #pragma unroll
      for (int m=0;m<4;m++)
        sA = __builtin_amdgcn_mfma_f32_32x32x16_bf16(kf[m], qfa[m], sA, 0, 0, 0);
    }

    PROC(sB, kt == qtb, mB, lB, aB0, aB1, vf0, vf1);
    if (doA) PROC(sA, kt == qta, mA, lA, aA0, aA1, vf0, vf1);

    #pragma unroll
    for (int m=0;m<4;m++) kf[m] = kf2[m];
    #pragma unroll
    for (int m=0;m<2;m++) { vf0[m] = v02[m]; vf1[m] = v12[m]; }
  }

  // epilogue: O[dv][q] regs -> LDS transpose -> coalesced global store
  const int b = bh >> 4, h = bh & 15;
  auto EPI = [&](int qt, float lS, const f32x16& o0, const f32x16& o1) {
    float inv = 1.0f / lS;
    ushort* o = &OT[w][0];
    #pragma unroll
    for (int r2=0;r2<8;r2++) {
      int r = 2*r2;
      int dv = (r&3) + ((r>>2)<<3) + 4*hi;
      *(unsigned*)&o[col*72 + dv]      = pk2(o0[r]*inv, o0[r+1]*inv);
      *(unsigned*)&o[col*72 + 32 + dv] = pk2(o1[r]*inv, o1[r+1]*inv);
    }
    #pragma unroll
    for (int it=0; it<4; ++it) {
      int q = it*8 + (l>>3), c8 = (l&7)*8;
      uint4 v = *(const uint4*)&o[q*72 + c8];
      int qg = qt*32 + q;
      *(uint4*)&Ob[(size_t)(b*1024+qg)*1024 + h*64 + c8] = v;
    }
  };
  EPI(qta, lA, aA0, aA1);
  EPI(qtb, lB, aB0, aB1);
}

extern "C" void kernel_launch(void* const* d_in, const int* in_sizes, int n_in,
                              void* d_out, int out_size, void* d_ws, size_t ws_size,
                              hipStream_t stream) {
  const float* query = (const float*)d_in[0];
  const float* Wq = (const float*)d_in[4];
  const float* bq = (const float*)d_in[5];
  const float* Wk = (const float*)d_in[6];
  const float* bk = (const float*)d_in[7];
  const float* Wv = (const float*)d_in[8];
  const float* bv = (const float*)d_in[9];
  const float* Wo = (const float*)d_in[10];
  const float* bo = (const float*)d_in[11];

  char* wsb = (char*)d_ws;
  ushort* Xb   = (ushort*)(wsb);                  // 16 MB
  ushort* Wqkv = (ushort*)(wsb + 16777216);       // 6 MB
  float*  Bqkv = (float*) (wsb + 23068672);       // 12 KB
  ushort* Wob  = (ushort*)(wsb + 23080960);       // 2 MB
  ushort* Qb   = (ushort*)(wsb + 25178112);       // 16 MB
  ushort* Kb   = (ushort*)(wsb + 41955328);       // 16 MB
  ushort* Vtb  = (ushort*)(wsb + 58732544);       // 16 MB  [bh][d][s]
  ushort* Ob   = (ushort*)(wsb + 75509760);       // 16 MB

  hipLaunchKernelGGL(pack_all_kern, dim3(5120), dim3(256), 0, stream,
                     query, Xb, Wq, Wk, Wv, bq, bk, bv, Wo, Wqkv, Bqkv, Wob);
  hipLaunchKernelGGL(gemm128_kern<0>, dim3(1536), dim3(256), 0, stream,
                     Xb, Wqkv, Bqkv, Qb, Kb, Vtb, (float*)nullptr);
  hipLaunchKernelGGL(attn_kern, dim3(512), dim3(256), 0, stream, Qb, Kb, Vtb, Ob);
  hipLaunchKernelGGL(gemm128_kern<1>, dim3(512), dim3(256), 0, stream,
                     Ob, Wob, bo, (ushort*)nullptr, (ushort*)nullptr, (ushort*)nullptr,
                     (float*)d_out);
}

// Round 13
// 152.669 us; speedup vs baseline: 1.2076x; 1.0767x over previous
//
#include <hip/hip_runtime.h>
#include <hip/hip_bf16.h>

#define B_ 8
#define S_ 1024
#define U_ 1024
#define H_ 16
#define DK_ 64

typedef __attribute__((ext_vector_type(8))) short short8;
typedef __attribute__((ext_vector_type(4))) float f32x4;
typedef __attribute__((ext_vector_type(16))) float f32x16;

__device__ inline ushort f2b(float x) {
  union { float f; unsigned u; } v; v.f = x;
  unsigned r = (v.u + 0x7FFFu + ((v.u >> 16) & 1u)) >> 16;
  return (ushort)r;
}
__device__ inline unsigned pk2(float lo, float hi) {
  return (unsigned)f2b(lo) | ((unsigned)f2b(hi) << 16);
}

__device__ inline void gld16(const ushort* g, ushort* l) {
  __builtin_amdgcn_global_load_lds((__attribute__((address_space(1))) void*)(g),
                                   (__attribute__((address_space(3))) void*)(l),
                                   16, 0, 0);
}

// ------------- fused pack: query fp32->bf16 + weight transpose ---------------
__global__ __launch_bounds__(256) void pack_all_kern(
    const float* __restrict__ X, ushort* __restrict__ Xb,
    const float* __restrict__ Wq, const float* __restrict__ Wk, const float* __restrict__ Wv,
    const float* __restrict__ bq, const float* __restrict__ bk, const float* __restrict__ bv,
    const float* __restrict__ Wo,
    ushort* __restrict__ Wqkv, float* __restrict__ Bqkv, ushort* __restrict__ Wob)
{
  __shared__ ushort tile[64*65];
  const int t = threadIdx.x;
  if (blockIdx.x < 4096) {
    int idx = blockIdx.x * 256 + t;
    const float4* src = (const float4*)X + (size_t)idx * 2;
    float4 a = src[0], b = src[1];
    ushort r[8];
    r[0]=f2b(a.x); r[1]=f2b(a.y); r[2]=f2b(a.z); r[3]=f2b(a.w);
    r[4]=f2b(b.x); r[5]=f2b(b.y); r[6]=f2b(b.z); r[7]=f2b(b.w);
    *(uint4*)(Xb + (size_t)idx*8) = *(uint4*)r;
    return;
  }
  const int bid = blockIdx.x - 4096;
  if (bid < 768) {
    int p = bid >> 8, rem = bid & 255;
    int h = rem >> 4, kc = rem & 15, k0 = kc*64;
    const float* Wsrc = (p==0) ? Wq : ((p==1) ? Wk : Wv);
    #pragma unroll
    for (int i = 0; i < 16; ++i) {
      int e = t + i*256;
      int r = e >> 6, d = e & 63;
      tile[d*65 + r] = f2b(Wsrc[h*65536 + (k0+r)*64 + d]);
    }
    __syncthreads();
    #pragma unroll
    for (int i = 0; i < 16; ++i) {
      int e = t + i*256;
      int d = e >> 6, r = e & 63;
      Wqkv[(size_t)(p*1024 + h*64 + d)*1024 + k0 + r] = tile[d*65 + r];
    }
    if (kc == 0 && t < 64) {
      const float* bsrc = (p==0) ? bq : ((p==1) ? bk : bv);
      Bqkv[p*1024 + h*64 + t] = bsrc[h*64 + t];
    }
  } else {
    int b2 = bid - 768;
    int nc = b2 >> 4, kc = b2 & 15;
    int n0 = nc*64, k0 = kc*64;
    #pragma unroll
    for (int i = 0; i < 16; ++i) {
      int e = t + i*256;
      int r = e >> 6, d = e & 63;
      tile[d*65 + r] = f2b(Wo[(size_t)(k0+r)*1024 + n0 + d]);
    }
    __syncthreads();
    #pragma unroll
    for (int i = 0; i < 16; ++i) {
      int e = t + i*256;
      int d = e >> 6, r = e & 63;
      Wob[(size_t)(n0+d)*1024 + k0 + r] = tile[d*65 + r];
    }
  }
}

// ---- GEMM: 128x128x32, TRIPLE buffer, 3 blocks/CU (round-12 best, frozen) --
template<int MODE>
__global__ __launch_bounds__(256, 3) void gemm128_kern(
    const ushort* __restrict__ A,
    const ushort* __restrict__ Bw,
    const float* __restrict__ bias,
    ushort* __restrict__ Qb, ushort* __restrict__ Kb, ushort* __restrict__ Vtb,
    float* __restrict__ outF)
{
  __shared__ __align__(16) ushort As[3][4096];
  __shared__ __align__(16) ushort Bs[3][4096];

  const int t = threadIdx.x;
  const int l = t & 63, w = t >> 6;
  const int wr = w >> 1, wc = w & 1;
  const int li = l & 15, c4 = l >> 4;

  int m0, n0;
  if (MODE==0) {
    int swz = (blockIdx.x & 7) * 192 + (blockIdx.x >> 3);
    int ms = swz / 192, rem = swz % 192;
    m0 = (ms*8 + (rem & 7)) * 128;  n0 = (rem >> 3) * 128;
  } else {
    int swz = (blockIdx.x & 7) * 64 + (blockIdx.x >> 3);
    int ms = swz / 64, rem = swz % 64;
    m0 = (ms*8 + (rem & 7)) * 128;  n0 = (rem >> 3) * 128;
  }

  f32x4 acc[4][4];
  #pragma unroll
  for (int i=0;i<4;i++)
    #pragma unroll
    for (int j=0;j<4;j++) acc[i][j] = (f32x4)0.0f;

  auto SA = [&](int buf, int kk) {
    #pragma unroll
    for (int p2=0;p2<2;++p2) {
      int n = p2*256 + t;
      int row = n >> 2, jj = (n & 3) ^ ((row >> 1) & 3);
      gld16(&A[(size_t)(m0 + row)*1024 + kk + jj*8], &As[buf][n*8]);
    }
  };
  auto SB = [&](int buf, int kk) {
    #pragma unroll
    for (int p2=0;p2<2;++p2) {
      int n = p2*256 + t;
      int row = n >> 2, jj = (n & 3) ^ ((row >> 1) & 3);
      gld16(&Bw[(size_t)(n0 + row)*1024 + kk + jj*8], &Bs[buf][n*8]);
    }
  };

  SA(0, 0);  SB(0, 0);
  SA(1, 32); SB(1, 32);

  for (int kt = 0; kt < 32; ++kt) {
    const int cur = kt % 3;
    asm volatile("s_waitcnt vmcnt(4)" ::: "memory");
    __builtin_amdgcn_s_barrier();
    __builtin_amdgcn_sched_barrier(0);

    short8 af[4], bf[4];
    #pragma unroll
    for (int i=0;i<4;i++) {
      int rA = wr*64 + i*16 + li;
      int rB = wc*64 + i*16 + li;
      af[i] = *(const short8*)&As[cur][rA*32 + ((c4 ^ ((rA>>1)&3))*8)];
      bf[i] = *(const short8*)&Bs[cur][rB*32 + ((c4 ^ ((rB>>1)&3))*8)];
    }
    __builtin_amdgcn_s_barrier();
    __builtin_amdgcn_sched_barrier(0);
    const int nb = (kt + 2) % 3;
    const int kk2 = ((kt + 2) & 31) * 32;
    SA(nb, kk2); SB(nb, kk2);

    __builtin_amdgcn_s_setprio(1);
    #pragma unroll
    for (int i=0;i<4;i++)
      #pragma unroll
      for (int j=0;j<4;j++)
        acc[i][j] = __builtin_amdgcn_mfma_f32_16x16x32_bf16(af[i], bf[j], acc[i][j], 0,0,0);
    __builtin_amdgcn_s_setprio(0);
  }

  #pragma unroll
  for (int i=0;i<4;i++) {
    int rbase = m0 + wr*64 + i*16 + c4*4;
    #pragma unroll
    for (int j=0;j<4;j++) {
      int col = n0 + wc*64 + j*16 + li;
      float bv = bias[col];
      if (MODE == 0) {
        int p = col >> 10, h = (col >> 6) & 15, d = col & 63;
        int b = rbase >> 10, s = rbase & 1023;
        if (p == 2) {
          ushort pk4[4];
          #pragma unroll
          for (int r=0;r<4;r++) pk4[r] = f2b(acc[i][j][r] + bv);
          *(uint2*)&Vtb[((size_t)((b*16+h)*64 + d))*1024 + s] = *(uint2*)pk4;
        } else {
          ushort* dst = (p==0) ? Qb : Kb;
          float sc = (p==0) ? 0.18033688011112042f : 1.0f;   // 0.125*log2(e)
          #pragma unroll
          for (int r=0;r<4;r++)
            dst[(((size_t)(b*16 + h))*1024 + s + r)*64 + d] = f2b((acc[i][j][r] + bv) * sc);
        }
      } else {
        #pragma unroll
        for (int r=0;r<4;r++)
          outF[(size_t)(rbase+r)*1024 + col] = acc[i][j][r] + bv;
      }
    }
  }
}

// ------- causal flash attention: block-staged K/V in LDS (L2-traffic fix) ---
// 512 blocks x 256 thr; block = (bh, g): its 4 waves own pairs (p,31-p),
// p = g*4+w -> near-identical kt ranges, so K/V tiles are staged ONCE per
// block into double-buffered LDS (7.6x L2 traffic cut vs per-wave loads).
// Reg-staged (padded strides 68/44 elems - gld_lds can't pad), T14 prefetch
// of tile kt+1 overlaps PROC, ONE __syncthreads per tile. Swapped QK^T
// (S[kv][q]) / swapped PV (O[d][q]); per-lane softmax + one shfl_xor(32);
// log2-domain scores; tree-shaped max/sum reductions.
__global__ __launch_bounds__(256, 2) void attn_kern(
    const ushort* __restrict__ Qb, const ushort* __restrict__ Kb,
    const ushort* __restrict__ Vt, ushort* __restrict__ Ob)
{
  __shared__ __align__(16) ushort Ks[2][32*68];   // [s][d] stride 68
  __shared__ __align__(16) ushort Vs[2][64*44];   // [dv][s32] stride 44
  __shared__ __align__(16) ushort Pb[4][32*40];   // per-wave P [q][kv]
  __shared__ __align__(16) ushort OT[4][32*72];   // per-wave epilogue transpose
  const int t = threadIdx.x, l = t & 63, w = t >> 6;
  const int bid = blockIdx.x;
  const int x = bid & 7, i0 = bid >> 3;
  const int bh = x*16 + (i0 >> 2);                // bh clustered per XCD
  const int g  = i0 & 3;
  const int p  = g*4 + w;
  const int qta = p, qtb = 31 - p;
  const int NT = 32 - g*4;                        // block-uniform tile count

  const int col = l & 31, hi = l >> 5;
  const ushort* Qp = Qb + (size_t)bh*65536;
  const ushort* Kp = Kb + (size_t)bh*65536;
  const ushort* Vp = Vt + (size_t)bh*65536;

  // staging coords: K tile 32x128B (1 uint4/thread), V tile 64x64B (1/thread)
  const int ks_row = t >> 3, ks_c = t & 7;
  const int vs_row = t >> 2, vs_c = t & 3;

  short8 qfa[4], qfb[4];
  #pragma unroll
  for (int m=0;m<4;m++) {
    qfa[m] = *(const short8*)&Qp[(size_t)(qta*32+col)*64 + m*16 + hi*8];
    qfb[m] = *(const short8*)&Qp[(size_t)(qtb*32+col)*64 + m*16 + hi*8];
  }

  f32x16 aA0 = (f32x16)0.0f, aA1 = (f32x16)0.0f;
  f32x16 aB0 = (f32x16)0.0f, aB1 = (f32x16)0.0f;
  float mA = -1e30f, lA = 0.0f, mB = -1e30f, lB = 0.0f;
  ushort* Pw = &Pb[w][0];

  auto PROC = [&](f32x16& s, bool diag, float& mR, float& lS,
                  f32x16& o0, f32x16& o1, const short8* vf0, const short8* vf1) {
    if (diag) {
      #pragma unroll
      for (int r=0;r<16;r++) {
        int kvl = (r&3) + ((r>>2)<<3) + 4*hi;
        s[r] = (kvl > col) ? -1e9f : s[r];
      }
    }
    float m8[8];
    #pragma unroll
    for (int r2=0;r2<8;r2++) m8[r2] = fmaxf(s[2*r2], s[2*r2+1]);
    #pragma unroll
    for (int r2=0;r2<4;r2++) m8[r2] = fmaxf(m8[r2], m8[r2+4]);
    float mx = fmaxf(fmaxf(m8[0],m8[1]), fmaxf(m8[2],m8[3]));
    mx = fmaxf(mx, __shfl_xor(mx, 32));
    if (__any(mx - mR > 8.0f)) {          // T13 defer-max (log2 units)
      float mN = fmaxf(mR, mx);
      float corr = __builtin_amdgcn_exp2f(mR - mN);
      mR = mN; lS *= corr;
      #pragma unroll
      for (int r=0;r<16;r++) { o0[r] *= corr; o1[r] *= corr; }
    }
    float pr[16];
    #pragma unroll
    for (int r=0;r<16;r++) pr[r] = __builtin_amdgcn_exp2f(s[r] - mR);
    float s8[8];
    #pragma unroll
    for (int r2=0;r2<8;r2++) s8[r2] = pr[2*r2] + pr[2*r2+1];
    #pragma unroll
    for (int r2=0;r2<4;r2++) s8[r2] += s8[r2+4];
    float rs = (s8[0]+s8[1]) + (s8[2]+s8[3]);
    rs += __shfl_xor(rs, 32);
    lS += rs;
    #pragma unroll
    for (int r2=0;r2<8;r2++) {
      int r = 2*r2;
      int kv = (r&3) + ((r>>2)<<3) + 4*hi;
      *(unsigned*)&Pw[col*40 + kv] = pk2(pr[r], pr[r+1]);
    }
    short8 pb0 = *(const short8*)&Pw[col*40 + hi*8];
    short8 pb1 = *(const short8*)&Pw[col*40 + 16 + hi*8];
    o0 = __builtin_amdgcn_mfma_f32_32x32x16_bf16(vf0[0], pb0, o0, 0,0,0);
    o0 = __builtin_amdgcn_mfma_f32_32x32x16_bf16(vf0[1], pb1, o0, 0,0,0);
    o1 = __builtin_amdgcn_mfma_f32_32x32x16_bf16(vf1[0], pb0, o1, 0,0,0);
    o1 = __builtin_amdgcn_mfma_f32_32x32x16_bf16(vf1[1], pb1, o1, 0,0,0);
  };

  { // stage tile 0 into buf 0
    uint4 k0v = *(const uint4*)&Kp[(size_t)ks_row*64 + ks_c*8];
    uint4 v0v = *(const uint4*)&Vp[(size_t)vs_row*1024 + vs_c*8];
    *(uint4*)&Ks[0][ks_row*68 + ks_c*8] = k0v;
    *(uint4*)&Vs[0][vs_row*44 + vs_c*8] = v0v;
  }
  __syncthreads();

  for (int kt = 0; kt < NT; ++kt) {
    const int cur = kt & 1;
    const bool pre = (kt + 1 < NT);
    uint4 kn2, vn2;
    if (pre) {   // T14: global prefetch of tile kt+1 (overlaps PROC below)
      kn2 = *(const uint4*)&Kp[(size_t)((kt+1)*32+ks_row)*64 + ks_c*8];
      vn2 = *(const uint4*)&Vp[(size_t)vs_row*1024 + (kt+1)*32 + vs_c*8];
    }

    short8 kf[4], vf0[2], vf1[2];
    #pragma unroll
    for (int m=0;m<4;m++)
      kf[m] = *(const short8*)&Ks[cur][col*68 + m*16 + hi*8];
    #pragma unroll
    for (int m=0;m<2;m++) {
      vf0[m] = *(const short8*)&Vs[cur][col*44 + m*16 + hi*8];
      vf1[m] = *(const short8*)&Vs[cur][(col+32)*44 + m*16 + hi*8];
    }

    const bool doB = (kt <= qtb), doA = (kt <= qta);
    if (doB) {
      f32x16 sB = (f32x16)0.0f;
      #pragma unroll
      for (int m=0;m<4;m++)
        sB = __builtin_amdgcn_mfma_f32_32x32x16_bf16(kf[m], qfb[m], sB, 0, 0, 0);
      if (doA) {
        f32x16 sA = (f32x16)0.0f;
        #pragma unroll
        for (int m=0;m<4;m++)
          sA = __builtin_amdgcn_mfma_f32_32x32x16_bf16(kf[m], qfa[m], sA, 0, 0, 0);
        PROC(sB, kt == qtb, mB, lB, aB0, aB1, vf0, vf1);
        PROC(sA, kt == qta, mA, lA, aA0, aA1, vf0, vf1);
      } else {
        PROC(sB, kt == qtb, mB, lB, aB0, aB1, vf0, vf1);
      }
    }

    if (pre) {   // write prefetched tile into other buffer
      *(uint4*)&Ks[cur^1][ks_row*68 + ks_c*8] = kn2;
      *(uint4*)&Vs[cur^1][vs_row*44 + vs_c*8] = vn2;
    }
    __syncthreads();
  }

  // epilogue: O[dv][q] regs -> LDS transpose -> coalesced global store
  const int b = bh >> 4, h = bh & 15;
  auto EPI = [&](int qt, float lS, const f32x16& o0, const f32x16& o1) {
    float inv = 1.0f / lS;
    ushort* o = &OT[w][0];
    #pragma unroll
    for (int r2=0;r2<8;r2++) {
      int r = 2*r2;
      int dv = (r&3) + ((r>>2)<<3) + 4*hi;
      *(unsigned*)&o[col*72 + dv]      = pk2(o0[r]*inv, o0[r+1]*inv);
      *(unsigned*)&o[col*72 + 32 + dv] = pk2(o1[r]*inv, o1[r+1]*inv);
    }
    #pragma unroll
    for (int it=0; it<4; ++it) {
      int q = it*8 + (l>>3), c8 = (l&7)*8;
      uint4 v = *(const uint4*)&o[q*72 + c8];
      int qg = qt*32 + q;
      *(uint4*)&Ob[(size_t)(b*1024+qg)*1024 + h*64 + c8] = v;
    }
  };
  EPI(qta, lA, aA0, aA1);
  EPI(qtb, lB, aB0, aB1);
}

extern "C" void kernel_launch(void* const* d_in, const int* in_sizes, int n_in,
                              void* d_out, int out_size, void* d_ws, size_t ws_size,
                              hipStream_t stream) {
  const float* query = (const float*)d_in[0];
  const float* Wq = (const float*)d_in[4];
  const float* bq = (const float*)d_in[5];
  const float* Wk = (const float*)d_in[6];
  const float* bk = (const float*)d_in[7];
  const float* Wv = (const float*)d_in[8];
  const float* bv = (const float*)d_in[9];
  const float* Wo = (const float*)d_in[10];
  const float* bo = (const float*)d_in[11];

  char* wsb = (char*)d_ws;
  ushort* Xb   = (ushort*)(wsb);                  // 16 MB
  ushort* Wqkv = (ushort*)(wsb + 16777216);       // 6 MB
  float*  Bqkv = (float*) (wsb + 23068672);       // 12 KB
  ushort* Wob  = (ushort*)(wsb + 23080960);       // 2 MB
  ushort* Qb   = (ushort*)(wsb + 25178112);       // 16 MB
  ushort* Kb   = (ushort*)(wsb + 41955328);       // 16 MB
  ushort* Vtb  = (ushort*)(wsb + 58732544);       // 16 MB  [bh][d][s]
  ushort* Ob   = (ushort*)(wsb + 75509760);       // 16 MB

  hipLaunchKernelGGL(pack_all_kern, dim3(5120), dim3(256), 0, stream,
                     query, Xb, Wq, Wk, Wv, bq, bk, bv, Wo, Wqkv, Bqkv, Wob);
  hipLaunchKernelGGL(gemm128_kern<0>, dim3(1536), dim3(256), 0, stream,
                     Xb, Wqkv, Bqkv, Qb, Kb, Vtb, (float*)nullptr);
  hipLaunchKernelGGL(attn_kern, dim3(512), dim3(256), 0, stream, Qb, Kb, Vtb, Ob);
  hipLaunchKernelGGL(gemm128_kern<1>, dim3(512), dim3(256), 0, stream,
                     Ob, Wob, bo, (ushort*)nullptr, (ushort*)nullptr, (ushort*)nullptr,
                     (float*)d_out);
}

// Round 14
// 147.689 us; speedup vs baseline: 1.2484x; 1.0337x over previous
//
#include <hip/hip_runtime.h>
#include <hip/hip_bf16.h>

#define B_ 8
#define S_ 1024
#define U_ 1024
#define H_ 16
#define DK_ 64

typedef __attribute__((ext_vector_type(8))) short short8;
typedef __attribute__((ext_vector_type(4))) float f32x4;
typedef __attribute__((ext_vector_type(16))) float f32x16;

__device__ inline ushort f2b(float x) {
  union { float f; unsigned u; } v; v.f = x;
  unsigned r = (v.u + 0x7FFFu + ((v.u >> 16) & 1u)) >> 16;
  return (ushort)r;
}
__device__ inline unsigned pk2(float lo, float hi) {
  return (unsigned)f2b(lo) | ((unsigned)f2b(hi) << 16);
}

__device__ inline void gld16(const ushort* g, ushort* l) {
  __builtin_amdgcn_global_load_lds((__attribute__((address_space(1))) void*)(g),
                                   (__attribute__((address_space(3))) void*)(l),
                                   16, 0, 0);
}

// ------------- fused pack: query fp32->bf16 + weight transpose ---------------
__global__ __launch_bounds__(256) void pack_all_kern(
    const float* __restrict__ X, ushort* __restrict__ Xb,
    const float* __restrict__ Wq, const float* __restrict__ Wk, const float* __restrict__ Wv,
    const float* __restrict__ bq, const float* __restrict__ bk, const float* __restrict__ bv,
    const float* __restrict__ Wo,
    ushort* __restrict__ Wqkv, float* __restrict__ Bqkv, ushort* __restrict__ Wob)
{
  __shared__ ushort tile[64*65];
  const int t = threadIdx.x;
  if (blockIdx.x < 4096) {
    int idx = blockIdx.x * 256 + t;
    const float4* src = (const float4*)X + (size_t)idx * 2;
    float4 a = src[0], b = src[1];
    ushort r[8];
    r[0]=f2b(a.x); r[1]=f2b(a.y); r[2]=f2b(a.z); r[3]=f2b(a.w);
    r[4]=f2b(b.x); r[5]=f2b(b.y); r[6]=f2b(b.z); r[7]=f2b(b.w);
    *(uint4*)(Xb + (size_t)idx*8) = *(uint4*)r;
    return;
  }
  const int bid = blockIdx.x - 4096;
  if (bid < 768) {
    int p = bid >> 8, rem = bid & 255;
    int h = rem >> 4, kc = rem & 15, k0 = kc*64;
    const float* Wsrc = (p==0) ? Wq : ((p==1) ? Wk : Wv);
    #pragma unroll
    for (int i = 0; i < 16; ++i) {
      int e = t + i*256;
      int r = e >> 6, d = e & 63;
      tile[d*65 + r] = f2b(Wsrc[h*65536 + (k0+r)*64 + d]);
    }
    __syncthreads();
    #pragma unroll
    for (int i = 0; i < 16; ++i) {
      int e = t + i*256;
      int d = e >> 6, r = e & 63;
      Wqkv[(size_t)(p*1024 + h*64 + d)*1024 + k0 + r] = tile[d*65 + r];
    }
    if (kc == 0 && t < 64) {
      const float* bsrc = (p==0) ? bq : ((p==1) ? bk : bv);
      Bqkv[p*1024 + h*64 + t] = bsrc[h*64 + t];
    }
  } else {
    int b2 = bid - 768;
    int nc = b2 >> 4, kc = b2 & 15;
    int n0 = nc*64, k0 = kc*64;
    #pragma unroll
    for (int i = 0; i < 16; ++i) {
      int e = t + i*256;
      int r = e >> 6, d = e & 63;
      tile[d*65 + r] = f2b(Wo[(size_t)(k0+r)*1024 + n0 + d]);
    }
    __syncthreads();
    #pragma unroll
    for (int i = 0; i < 16; ++i) {
      int e = t + i*256;
      int d = e >> 6, r = e & 63;
      Wob[(size_t)(n0+d)*1024 + k0 + r] = tile[d*65 + r];
    }
  }
}

// ---- QKV GEMM: 256x128x32, per-wave C=128x64, triple buffer, 2 blk/CU ------
// 256 thr = 4 waves (2M x 2N), per-wave C = 128x64 -> 0.375 LDS reads/MFMA
// (vs 0.5 at 64x64): LDS-read-throughput was the binding resource. LDS: 3 buf
// x (A[256][32]+B[128][32]) = 72 KB -> 2 blk/CU. Per K-step: vmcnt(6)
// [counted: tile kt landed, kt+1's 6 in flight] -> bar -> 12 ds_read -> bar ->
// stage kt+2 (6 gld_lds) -> 32 MFMA. Never vmcnt(0). XOR-chunk swizzle
// both-sides (rule #21). Grid 768 = 3 clean per-CU fills.
__global__ __launch_bounds__(256, 2) void gemmw_kern(
    const ushort* __restrict__ A,
    const ushort* __restrict__ Bw,
    const float* __restrict__ bias,
    ushort* __restrict__ Qb, ushort* __restrict__ Kb, ushort* __restrict__ Vtb)
{
  __shared__ __align__(16) ushort As[3][8192];   // [buf][(row 0..255)*32+col]
  __shared__ __align__(16) ushort Bs[3][4096];   // [buf][(row 0..127)*32+col]

  const int t = threadIdx.x;
  const int l = t & 63, w = t >> 6;
  const int wr = w >> 1, wc = w & 1;
  const int li = l & 15, c4 = l >> 4;

  // raster: 768 blocks = 32m x 24n; XCD chunk 96 = 4m x 24n (bijective)
  const int swz = (blockIdx.x & 7) * 96 + (blockIdx.x >> 3);
  const int ms = swz / 96, rem = swz % 96;
  const int m0 = (ms*4 + (rem & 3)) * 256;
  const int n0 = (rem >> 2) * 128;

  f32x4 acc[8][4];
  #pragma unroll
  for (int i=0;i<8;i++)
    #pragma unroll
    for (int j=0;j<4;j++) acc[i][j] = (f32x4)0.0f;

  auto SA = [&](int buf, int kk) {      // 256x32 tile: 1024 chunks, 4/thread
    #pragma unroll
    for (int p2=0;p2<4;++p2) {
      int n = p2*256 + t;
      int row = n >> 2, jj = (n & 3) ^ ((row >> 1) & 3);
      gld16(&A[(size_t)(m0 + row)*1024 + kk + jj*8], &As[buf][n*8]);
    }
  };
  auto SB = [&](int buf, int kk) {      // 128x32 tile: 512 chunks, 2/thread
    #pragma unroll
    for (int p2=0;p2<2;++p2) {
      int n = p2*256 + t;
      int row = n >> 2, jj = (n & 3) ^ ((row >> 1) & 3);
      gld16(&Bw[(size_t)(n0 + row)*1024 + kk + jj*8], &Bs[buf][n*8]);
    }
  };

  SA(0, 0);  SB(0, 0);
  SA(1, 32); SB(1, 32);

  for (int kt = 0; kt < 32; ++kt) {
    const int cur = kt % 3;
    asm volatile("s_waitcnt vmcnt(6)" ::: "memory");  // tile kt landed; kt+1 in flight
    __builtin_amdgcn_s_barrier();
    __builtin_amdgcn_sched_barrier(0);

    short8 af[8], bf[4];
    #pragma unroll
    for (int i=0;i<8;i++) {
      int rA = wr*128 + i*16 + li;
      af[i] = *(const short8*)&As[cur][rA*32 + ((c4 ^ ((rA>>1)&3))*8)];
    }
    #pragma unroll
    for (int j=0;j<4;j++) {
      int rB = wc*64 + j*16 + li;
      bf[j] = *(const short8*)&Bs[cur][rB*32 + ((c4 ^ ((rB>>1)&3))*8)];
    }
    __builtin_amdgcn_s_barrier();            // all waves done reading slot (kt+2)%3
    __builtin_amdgcn_sched_barrier(0);
    const int nb = (kt + 2) % 3;
    const int kk2 = ((kt + 2) & 31) * 32;    // tail wraps: dummy, never read
    SA(nb, kk2); SB(nb, kk2);

    __builtin_amdgcn_s_setprio(1);
    #pragma unroll
    for (int i=0;i<8;i++)
      #pragma unroll
      for (int j=0;j<4;j++)
        acc[i][j] = __builtin_amdgcn_mfma_f32_16x16x32_bf16(af[i], bf[j], acc[i][j], 0,0,0);
    __builtin_amdgcn_s_setprio(0);
  }

  #pragma unroll
  for (int i=0;i<8;i++) {
    int rbase = m0 + wr*128 + i*16 + c4*4;
    #pragma unroll
    for (int j=0;j<4;j++) {
      int col = n0 + wc*64 + j*16 + li;
      float bv = bias[col];
      int p = col >> 10, h = (col >> 6) & 15, d = col & 63;
      int b = rbase >> 10, s = rbase & 1023;
      if (p == 2) {            // V -> transposed [bh][d][s], 8B packed store
        ushort pk4[4];
        #pragma unroll
        for (int r=0;r<4;r++) pk4[r] = f2b(acc[i][j][r] + bv);
        *(uint2*)&Vtb[((size_t)((b*16+h)*64 + d))*1024 + s] = *(uint2*)pk4;
      } else {
        ushort* dst = (p==0) ? Qb : Kb;
        float sc = (p==0) ? 0.18033688011112042f : 1.0f;   // 0.125*log2(e)
        #pragma unroll
        for (int r=0;r<4;r++)
          dst[(((size_t)(b*16 + h))*1024 + s + r)*64 + d] = f2b((acc[i][j][r] + bv) * sc);
      }
    }
  }
}

// ---- out-proj GEMM: 128x128x32 triple buffer (round-12 best, frozen) -------
template<int MODE>
__global__ __launch_bounds__(256, 3) void gemm128_kern(
    const ushort* __restrict__ A,
    const ushort* __restrict__ Bw,
    const float* __restrict__ bias,
    ushort* __restrict__ Qb, ushort* __restrict__ Kb, ushort* __restrict__ Vtb,
    float* __restrict__ outF)
{
  __shared__ __align__(16) ushort As[3][4096];
  __shared__ __align__(16) ushort Bs[3][4096];

  const int t = threadIdx.x;
  const int l = t & 63, w = t >> 6;
  const int wr = w >> 1, wc = w & 1;
  const int li = l & 15, c4 = l >> 4;

  int m0, n0;
  {
    int swz = (blockIdx.x & 7) * 64 + (blockIdx.x >> 3);
    int ms = swz / 64, rem = swz % 64;
    m0 = (ms*8 + (rem & 7)) * 128;  n0 = (rem >> 3) * 128;
  }

  f32x4 acc[4][4];
  #pragma unroll
  for (int i=0;i<4;i++)
    #pragma unroll
    for (int j=0;j<4;j++) acc[i][j] = (f32x4)0.0f;

  auto SA = [&](int buf, int kk) {
    #pragma unroll
    for (int p2=0;p2<2;++p2) {
      int n = p2*256 + t;
      int row = n >> 2, jj = (n & 3) ^ ((row >> 1) & 3);
      gld16(&A[(size_t)(m0 + row)*1024 + kk + jj*8], &As[buf][n*8]);
    }
  };
  auto SB = [&](int buf, int kk) {
    #pragma unroll
    for (int p2=0;p2<2;++p2) {
      int n = p2*256 + t;
      int row = n >> 2, jj = (n & 3) ^ ((row >> 1) & 3);
      gld16(&Bw[(size_t)(n0 + row)*1024 + kk + jj*8], &Bs[buf][n*8]);
    }
  };

  SA(0, 0);  SB(0, 0);
  SA(1, 32); SB(1, 32);

  for (int kt = 0; kt < 32; ++kt) {
    const int cur = kt % 3;
    asm volatile("s_waitcnt vmcnt(4)" ::: "memory");
    __builtin_amdgcn_s_barrier();
    __builtin_amdgcn_sched_barrier(0);

    short8 af[4], bf[4];
    #pragma unroll
    for (int i=0;i<4;i++) {
      int rA = wr*64 + i*16 + li;
      int rB = wc*64 + i*16 + li;
      af[i] = *(const short8*)&As[cur][rA*32 + ((c4 ^ ((rA>>1)&3))*8)];
      bf[i] = *(const short8*)&Bs[cur][rB*32 + ((c4 ^ ((rB>>1)&3))*8)];
    }
    __builtin_amdgcn_s_barrier();
    __builtin_amdgcn_sched_barrier(0);
    const int nb = (kt + 2) % 3;
    const int kk2 = ((kt + 2) & 31) * 32;
    SA(nb, kk2); SB(nb, kk2);

    __builtin_amdgcn_s_setprio(1);
    #pragma unroll
    for (int i=0;i<4;i++)
      #pragma unroll
      for (int j=0;j<4;j++)
        acc[i][j] = __builtin_amdgcn_mfma_f32_16x16x32_bf16(af[i], bf[j], acc[i][j], 0,0,0);
    __builtin_amdgcn_s_setprio(0);
  }

  #pragma unroll
  for (int i=0;i<4;i++) {
    int rbase = m0 + wr*64 + i*16 + c4*4;
    #pragma unroll
    for (int j=0;j<4;j++) {
      int col = n0 + wc*64 + j*16 + li;
      float bv = bias[col];
      #pragma unroll
      for (int r=0;r<4;r++)
        outF[(size_t)(rbase+r)*1024 + col] = acc[i][j][r] + bv;
    }
  }
}

// ------- causal flash attention: block-staged K/V in LDS (round-13 best) ----
__global__ __launch_bounds__(256, 2) void attn_kern(
    const ushort* __restrict__ Qb, const ushort* __restrict__ Kb,
    const ushort* __restrict__ Vt, ushort* __restrict__ Ob)
{
  __shared__ __align__(16) ushort Ks[2][32*68];   // [s][d] stride 68
  __shared__ __align__(16) ushort Vs[2][64*44];   // [dv][s32] stride 44
  __shared__ __align__(16) ushort Pb[4][32*40];   // per-wave P [q][kv]
  __shared__ __align__(16) ushort OT[4][32*72];   // per-wave epilogue transpose
  const int t = threadIdx.x, l = t & 63, w = t >> 6;
  const int bid = blockIdx.x;
  const int x = bid & 7, i0 = bid >> 3;
  const int bh = x*16 + (i0 >> 2);                // bh clustered per XCD
  const int g  = i0 & 3;
  const int p  = g*4 + w;
  const int qta = p, qtb = 31 - p;
  const int NT = 32 - g*4;                        // block-uniform tile count

  const int col = l & 31, hi = l >> 5;
  const ushort* Qp = Qb + (size_t)bh*65536;
  const ushort* Kp = Kb + (size_t)bh*65536;
  const ushort* Vp = Vt + (size_t)bh*65536;

  const int ks_row = t >> 3, ks_c = t & 7;
  const int vs_row = t >> 2, vs_c = t & 3;

  short8 qfa[4], qfb[4];
  #pragma unroll
  for (int m=0;m<4;m++) {
    qfa[m] = *(const short8*)&Qp[(size_t)(qta*32+col)*64 + m*16 + hi*8];
    qfb[m] = *(const short8*)&Qp[(size_t)(qtb*32+col)*64 + m*16 + hi*8];
  }

  f32x16 aA0 = (f32x16)0.0f, aA1 = (f32x16)0.0f;
  f32x16 aB0 = (f32x16)0.0f, aB1 = (f32x16)0.0f;
  float mA = -1e30f, lA = 0.0f, mB = -1e30f, lB = 0.0f;
  ushort* Pw = &Pb[w][0];

  auto PROC = [&](f32x16& s, bool diag, float& mR, float& lS,
                  f32x16& o0, f32x16& o1, const short8* vf0, const short8* vf1) {
    if (diag) {
      #pragma unroll
      for (int r=0;r<16;r++) {
        int kvl = (r&3) + ((r>>2)<<3) + 4*hi;
        s[r] = (kvl > col) ? -1e9f : s[r];
      }
    }
    float m8[8];
    #pragma unroll
    for (int r2=0;r2<8;r2++) m8[r2] = fmaxf(s[2*r2], s[2*r2+1]);
    #pragma unroll
    for (int r2=0;r2<4;r2++) m8[r2] = fmaxf(m8[r2], m8[r2+4]);
    float mx = fmaxf(fmaxf(m8[0],m8[1]), fmaxf(m8[2],m8[3]));
    mx = fmaxf(mx, __shfl_xor(mx, 32));
    if (__any(mx - mR > 8.0f)) {          // T13 defer-max (log2 units)
      float mN = fmaxf(mR, mx);
      float corr = __builtin_amdgcn_exp2f(mR - mN);
      mR = mN; lS *= corr;
      #pragma unroll
      for (int r=0;r<16;r++) { o0[r] *= corr; o1[r] *= corr; }
    }
    float pr[16];
    #pragma unroll
    for (int r=0;r<16;r++) pr[r] = __builtin_amdgcn_exp2f(s[r] - mR);
    float s8[8];
    #pragma unroll
    for (int r2=0;r2<8;r2++) s8[r2] = pr[2*r2] + pr[2*r2+1];
    #pragma unroll
    for (int r2=0;r2<4;r2++) s8[r2] += s8[r2+4];
    float rs = (s8[0]+s8[1]) + (s8[2]+s8[3]);
    rs += __shfl_xor(rs, 32);
    lS += rs;
    #pragma unroll
    for (int r2=0;r2<8;r2++) {
      int r = 2*r2;
      int kv = (r&3) + ((r>>2)<<3) + 4*hi;
      *(unsigned*)&Pw[col*40 + kv] = pk2(pr[r], pr[r+1]);
    }
    short8 pb0 = *(const short8*)&Pw[col*40 + hi*8];
    short8 pb1 = *(const short8*)&Pw[col*40 + 16 + hi*8];
    o0 = __builtin_amdgcn_mfma_f32_32x32x16_bf16(vf0[0], pb0, o0, 0,0,0);
    o0 = __builtin_amdgcn_mfma_f32_32x32x16_bf16(vf0[1], pb1, o0, 0,0,0);
    o1 = __builtin_amdgcn_mfma_f32_32x32x16_bf16(vf1[0], pb0, o1, 0,0,0);
    o1 = __builtin_amdgcn_mfma_f32_32x32x16_bf16(vf1[1], pb1, o1, 0,0,0);
  };

  { // stage tile 0 into buf 0
    uint4 k0v = *(const uint4*)&Kp[(size_t)ks_row*64 + ks_c*8];
    uint4 v0v = *(const uint4*)&Vp[(size_t)vs_row*1024 + vs_c*8];
    *(uint4*)&Ks[0][ks_row*68 + ks_c*8] = k0v;
    *(uint4*)&Vs[0][vs_row*44 + vs_c*8] = v0v;
  }
  __syncthreads();

  for (int kt = 0; kt < NT; ++kt) {
    const int cur = kt & 1;
    const bool pre = (kt + 1 < NT);
    uint4 kn2, vn2;
    if (pre) {   // T14: global prefetch of tile kt+1 (overlaps PROC below)
      kn2 = *(const uint4*)&Kp[(size_t)((kt+1)*32+ks_row)*64 + ks_c*8];
      vn2 = *(const uint4*)&Vp[(size_t)vs_row*1024 + (kt+1)*32 + vs_c*8];
    }

    short8 kf[4], vf0[2], vf1[2];
    #pragma unroll
    for (int m=0;m<4;m++)
      kf[m] = *(const short8*)&Ks[cur][col*68 + m*16 + hi*8];
    #pragma unroll
    for (int m=0;m<2;m++) {
      vf0[m] = *(const short8*)&Vs[cur][col*44 + m*16 + hi*8];
      vf1[m] = *(const short8*)&Vs[cur][(col+32)*44 + m*16 + hi*8];
    }

    const bool doB = (kt <= qtb), doA = (kt <= qta);
    if (doB) {
      f32x16 sB = (f32x16)0.0f;
      #pragma unroll
      for (int m=0;m<4;m++)
        sB = __builtin_amdgcn_mfma_f32_32x32x16_bf16(kf[m], qfb[m], sB, 0, 0, 0);
      if (doA) {
        f32x16 sA = (f32x16)0.0f;
        #pragma unroll
        for (int m=0;m<4;m++)
          sA = __builtin_amdgcn_mfma_f32_32x32x16_bf16(kf[m], qfa[m], sA, 0, 0, 0);
        PROC(sB, kt == qtb, mB, lB, aB0, aB1, vf0, vf1);
        PROC(sA, kt == qta, mA, lA, aA0, aA1, vf0, vf1);
      } else {
        PROC(sB, kt == qtb, mB, lB, aB0, aB1, vf0, vf1);
      }
    }

    if (pre) {
      *(uint4*)&Ks[cur^1][ks_row*68 + ks_c*8] = kn2;
      *(uint4*)&Vs[cur^1][vs_row*44 + vs_c*8] = vn2;
    }
    __syncthreads();
  }

  // epilogue: O[dv][q] regs -> LDS transpose -> coalesced global store
  const int b = bh >> 4, h = bh & 15;
  auto EPI = [&](int qt, float lS, const f32x16& o0, const f32x16& o1) {
    float inv = 1.0f / lS;
    ushort* o = &OT[w][0];
    #pragma unroll
    for (int r2=0;r2<8;r2++) {
      int r = 2*r2;
      int dv = (r&3) + ((r>>2)<<3) + 4*hi;
      *(unsigned*)&o[col*72 + dv]      = pk2(o0[r]*inv, o0[r+1]*inv);
      *(unsigned*)&o[col*72 + 32 + dv] = pk2(o1[r]*inv, o1[r+1]*inv);
    }
    #pragma unroll
    for (int it=0; it<4; ++it) {
      int q = it*8 + (l>>3), c8 = (l&7)*8;
      uint4 v = *(const uint4*)&o[q*72 + c8];
      int qg = qt*32 + q;
      *(uint4*)&Ob[(size_t)(b*1024+qg)*1024 + h*64 + c8] = v;
    }
  };
  EPI(qta, lA, aA0, aA1);
  EPI(qtb, lB, aB0, aB1);
}

extern "C" void kernel_launch(void* const* d_in, const int* in_sizes, int n_in,
                              void* d_out, int out_size, void* d_ws, size_t ws_size,
                              hipStream_t stream) {
  const float* query = (const float*)d_in[0];
  const float* Wq = (const float*)d_in[4];
  const float* bq = (const float*)d_in[5];
  const float* Wk = (const float*)d_in[6];
  const float* bk = (const float*)d_in[7];
  const float* Wv = (const float*)d_in[8];
  const float* bv = (const float*)d_in[9];
  const float* Wo = (const float*)d_in[10];
  const float* bo = (const float*)d_in[11];

  char* wsb = (char*)d_ws;
  ushort* Xb   = (ushort*)(wsb);                  // 16 MB
  ushort* Wqkv = (ushort*)(wsb + 16777216);       // 6 MB
  float*  Bqkv = (float*) (wsb + 23068672);       // 12 KB
  ushort* Wob  = (ushort*)(wsb + 23080960);       // 2 MB
  ushort* Qb   = (ushort*)(wsb + 25178112);       // 16 MB
  ushort* Kb   = (ushort*)(wsb + 41955328);       // 16 MB
  ushort* Vtb  = (ushort*)(wsb + 58732544);       // 16 MB  [bh][d][s]
  ushort* Ob   = (ushort*)(wsb + 75509760);       // 16 MB

  hipLaunchKernelGGL(pack_all_kern, dim3(5120), dim3(256), 0, stream,
                     query, Xb, Wq, Wk, Wv, bq, bk, bv, Wo, Wqkv, Bqkv, Wob);
  hipLaunchKernelGGL(gemmw_kern, dim3(768), dim3(256), 0, stream,
                     Xb, Wqkv, Bqkv, Qb, Kb, Vtb);
  hipLaunchKernelGGL(attn_kern, dim3(512), dim3(256), 0, stream, Qb, Kb, Vtb, Ob);
  hipLaunchKernelGGL(gemm128_kern<1>, dim3(512), dim3(256), 0, stream,
                     Ob, Wob, bo, (ushort*)nullptr, (ushort*)nullptr, (ushort*)nullptr,
                     (float*)d_out);
}

// Round 15
// 143.106 us; speedup vs baseline: 1.2884x; 1.0320x over previous
//
#include <hip/hip_runtime.h>
#include <hip/hip_bf16.h>

#define B_ 8
#define S_ 1024
#define U_ 1024
#define H_ 16
#define DK_ 64

typedef __attribute__((ext_vector_type(8))) short short8;
typedef __attribute__((ext_vector_type(4))) float f32x4;
typedef __attribute__((ext_vector_type(16))) float f32x16;

__device__ inline ushort f2b(float x) {
  union { float f; unsigned u; } v; v.f = x;
  unsigned r = (v.u + 0x7FFFu + ((v.u >> 16) & 1u)) >> 16;
  return (ushort)r;
}
// packed bf16 convert (RNE, same as f2b) - 1 instr instead of ~8
__device__ inline unsigned cvtpk(float lo, float hi) {
  unsigned r;
  asm("v_cvt_pk_bf16_f32 %0, %1, %2" : "=v"(r) : "v"(lo), "v"(hi));
  return r;
}

__device__ inline void gld16(const ushort* g, ushort* l) {
  __builtin_amdgcn_global_load_lds((__attribute__((address_space(1))) void*)(g),
                                   (__attribute__((address_space(3))) void*)(l),
                                   16, 0, 0);
}

// ------------- fused pack: query fp32->bf16 + weight transpose ---------------
__global__ __launch_bounds__(256) void pack_all_kern(
    const float* __restrict__ X, ushort* __restrict__ Xb,
    const float* __restrict__ Wq, const float* __restrict__ Wk, const float* __restrict__ Wv,
    const float* __restrict__ bq, const float* __restrict__ bk, const float* __restrict__ bv,
    const float* __restrict__ Wo,
    ushort* __restrict__ Wqkv, float* __restrict__ Bqkv, ushort* __restrict__ Wob)
{
  __shared__ ushort tile[64*65];
  const int t = threadIdx.x;
  if (blockIdx.x < 4096) {
    int idx = blockIdx.x * 256 + t;
    const float4* src = (const float4*)X + (size_t)idx * 2;
    float4 a = src[0], b = src[1];
    ushort r[8];
    r[0]=f2b(a.x); r[1]=f2b(a.y); r[2]=f2b(a.z); r[3]=f2b(a.w);
    r[4]=f2b(b.x); r[5]=f2b(b.y); r[6]=f2b(b.z); r[7]=f2b(b.w);
    *(uint4*)(Xb + (size_t)idx*8) = *(uint4*)r;
    return;
  }
  const int bid = blockIdx.x - 4096;
  if (bid < 768) {
    int p = bid >> 8, rem = bid & 255;
    int h = rem >> 4, kc = rem & 15, k0 = kc*64;
    const float* Wsrc = (p==0) ? Wq : ((p==1) ? Wk : Wv);
    #pragma unroll
    for (int i = 0; i < 16; ++i) {
      int e = t + i*256;
      int r = e >> 6, d = e & 63;
      tile[d*65 + r] = f2b(Wsrc[h*65536 + (k0+r)*64 + d]);
    }
    __syncthreads();
    #pragma unroll
    for (int i = 0; i < 16; ++i) {
      int e = t + i*256;
      int d = e >> 6, r = e & 63;
      Wqkv[(size_t)(p*1024 + h*64 + d)*1024 + k0 + r] = tile[d*65 + r];
    }
    if (kc == 0 && t < 64) {
      const float* bsrc = (p==0) ? bq : ((p==1) ? bk : bv);
      Bqkv[p*1024 + h*64 + t] = bsrc[h*64 + t];
    }
  } else {
    int b2 = bid - 768;
    int nc = b2 >> 4, kc = b2 & 15;
    int n0 = nc*64, k0 = kc*64;
    #pragma unroll
    for (int i = 0; i < 16; ++i) {
      int e = t + i*256;
      int r = e >> 6, d = e & 63;
      tile[d*65 + r] = f2b(Wo[(size_t)(k0+r)*1024 + n0 + d]);
    }
    __syncthreads();
    #pragma unroll
    for (int i = 0; i < 16; ++i) {
      int e = t + i*256;
      int d = e >> 6, r = e & 63;
      Wob[(size_t)(n0+d)*1024 + k0 + r] = tile[d*65 + r];
    }
  }
}

// ---- QKV GEMM: 256x128x32, per-wave C=128x64, triple buffer (r14 frozen) ---
__global__ __launch_bounds__(256, 2) void gemmw_kern(
    const ushort* __restrict__ A,
    const ushort* __restrict__ Bw,
    const float* __restrict__ bias,
    ushort* __restrict__ Qb, ushort* __restrict__ Kb, ushort* __restrict__ Vtb)
{
  __shared__ __align__(16) ushort As[3][8192];   // [buf][(row 0..255)*32+col]
  __shared__ __align__(16) ushort Bs[3][4096];   // [buf][(row 0..127)*32+col]

  const int t = threadIdx.x;
  const int l = t & 63, w = t >> 6;
  const int wr = w >> 1, wc = w & 1;
  const int li = l & 15, c4 = l >> 4;

  const int swz = (blockIdx.x & 7) * 96 + (blockIdx.x >> 3);
  const int ms = swz / 96, rem = swz % 96;
  const int m0 = (ms*4 + (rem & 3)) * 256;
  const int n0 = (rem >> 2) * 128;

  f32x4 acc[8][4];
  #pragma unroll
  for (int i=0;i<8;i++)
    #pragma unroll
    for (int j=0;j<4;j++) acc[i][j] = (f32x4)0.0f;

  auto SA = [&](int buf, int kk) {
    #pragma unroll
    for (int p2=0;p2<4;++p2) {
      int n = p2*256 + t;
      int row = n >> 2, jj = (n & 3) ^ ((row >> 1) & 3);
      gld16(&A[(size_t)(m0 + row)*1024 + kk + jj*8], &As[buf][n*8]);
    }
  };
  auto SB = [&](int buf, int kk) {
    #pragma unroll
    for (int p2=0;p2<2;++p2) {
      int n = p2*256 + t;
      int row = n >> 2, jj = (n & 3) ^ ((row >> 1) & 3);
      gld16(&Bw[(size_t)(n0 + row)*1024 + kk + jj*8], &Bs[buf][n*8]);
    }
  };

  SA(0, 0);  SB(0, 0);
  SA(1, 32); SB(1, 32);

  for (int kt = 0; kt < 32; ++kt) {
    const int cur = kt % 3;
    asm volatile("s_waitcnt vmcnt(6)" ::: "memory");
    __builtin_amdgcn_s_barrier();
    __builtin_amdgcn_sched_barrier(0);

    short8 af[8], bf[4];
    #pragma unroll
    for (int i=0;i<8;i++) {
      int rA = wr*128 + i*16 + li;
      af[i] = *(const short8*)&As[cur][rA*32 + ((c4 ^ ((rA>>1)&3))*8)];
    }
    #pragma unroll
    for (int j=0;j<4;j++) {
      int rB = wc*64 + j*16 + li;
      bf[j] = *(const short8*)&Bs[cur][rB*32 + ((c4 ^ ((rB>>1)&3))*8)];
    }
    __builtin_amdgcn_s_barrier();
    __builtin_amdgcn_sched_barrier(0);
    const int nb = (kt + 2) % 3;
    const int kk2 = ((kt + 2) & 31) * 32;
    SA(nb, kk2); SB(nb, kk2);

    __builtin_amdgcn_s_setprio(1);
    #pragma unroll
    for (int i=0;i<8;i++)
      #pragma unroll
      for (int j=0;j<4;j++)
        acc[i][j] = __builtin_amdgcn_mfma_f32_16x16x32_bf16(af[i], bf[j], acc[i][j], 0,0,0);
    __builtin_amdgcn_s_setprio(0);
  }

  #pragma unroll
  for (int i=0;i<8;i++) {
    int rbase = m0 + wr*128 + i*16 + c4*4;
    #pragma unroll
    for (int j=0;j<4;j++) {
      int col = n0 + wc*64 + j*16 + li;
      float bv = bias[col];
      int p = col >> 10, h = (col >> 6) & 15, d = col & 63;
      int b = rbase >> 10, s = rbase & 1023;
      if (p == 2) {            // V -> transposed [bh][d][s], 8B packed store
        unsigned pk4[2];
        pk4[0] = cvtpk(acc[i][j][0] + bv, acc[i][j][1] + bv);
        pk4[1] = cvtpk(acc[i][j][2] + bv, acc[i][j][3] + bv);
        *(uint2*)&Vtb[((size_t)((b*16+h)*64 + d))*1024 + s] = *(uint2*)pk4;
      } else {
        ushort* dst = (p==0) ? Qb : Kb;
        float sc = (p==0) ? 0.18033688011112042f : 1.0f;   // 0.125*log2(e)
        #pragma unroll
        for (int r=0;r<4;r++)
          dst[(((size_t)(b*16 + h))*1024 + s + r)*64 + d] = f2b((acc[i][j][r] + bv) * sc);
      }
    }
  }
}

// ---- out-proj GEMM: 128x128x32 triple buffer (frozen) ----------------------
template<int MODE>
__global__ __launch_bounds__(256, 3) void gemm128_kern(
    const ushort* __restrict__ A,
    const ushort* __restrict__ Bw,
    const float* __restrict__ bias,
    ushort* __restrict__ Qb, ushort* __restrict__ Kb, ushort* __restrict__ Vtb,
    float* __restrict__ outF)
{
  __shared__ __align__(16) ushort As[3][4096];
  __shared__ __align__(16) ushort Bs[3][4096];

  const int t = threadIdx.x;
  const int l = t & 63, w = t >> 6;
  const int wr = w >> 1, wc = w & 1;
  const int li = l & 15, c4 = l >> 4;

  int m0, n0;
  {
    int swz = (blockIdx.x & 7) * 64 + (blockIdx.x >> 3);
    int ms = swz / 64, rem = swz % 64;
    m0 = (ms*8 + (rem & 7)) * 128;  n0 = (rem >> 3) * 128;
  }

  f32x4 acc[4][4];
  #pragma unroll
  for (int i=0;i<4;i++)
    #pragma unroll
    for (int j=0;j<4;j++) acc[i][j] = (f32x4)0.0f;

  auto SA = [&](int buf, int kk) {
    #pragma unroll
    for (int p2=0;p2<2;++p2) {
      int n = p2*256 + t;
      int row = n >> 2, jj = (n & 3) ^ ((row >> 1) & 3);
      gld16(&A[(size_t)(m0 + row)*1024 + kk + jj*8], &As[buf][n*8]);
    }
  };
  auto SB = [&](int buf, int kk) {
    #pragma unroll
    for (int p2=0;p2<2;++p2) {
      int n = p2*256 + t;
      int row = n >> 2, jj = (n & 3) ^ ((row >> 1) & 3);
      gld16(&Bw[(size_t)(n0 + row)*1024 + kk + jj*8], &Bs[buf][n*8]);
    }
  };

  SA(0, 0);  SB(0, 0);
  SA(1, 32); SB(1, 32);

  for (int kt = 0; kt < 32; ++kt) {
    const int cur = kt % 3;
    asm volatile("s_waitcnt vmcnt(4)" ::: "memory");
    __builtin_amdgcn_s_barrier();
    __builtin_amdgcn_sched_barrier(0);

    short8 af[4], bf[4];
    #pragma unroll
    for (int i=0;i<4;i++) {
      int rA = wr*64 + i*16 + li;
      int rB = wc*64 + i*16 + li;
      af[i] = *(const short8*)&As[cur][rA*32 + ((c4 ^ ((rA>>1)&3))*8)];
      bf[i] = *(const short8*)&Bs[cur][rB*32 + ((c4 ^ ((rB>>1)&3))*8)];
    }
    __builtin_amdgcn_s_barrier();
    __builtin_amdgcn_sched_barrier(0);
    const int nb = (kt + 2) % 3;
    const int kk2 = ((kt + 2) & 31) * 32;
    SA(nb, kk2); SB(nb, kk2);

    __builtin_amdgcn_s_setprio(1);
    #pragma unroll
    for (int i=0;i<4;i++)
      #pragma unroll
      for (int j=0;j<4;j++)
        acc[i][j] = __builtin_amdgcn_mfma_f32_16x16x32_bf16(af[i], bf[j], acc[i][j], 0,0,0);
    __builtin_amdgcn_s_setprio(0);
  }

  #pragma unroll
  for (int i=0;i<4;i++) {
    int rbase = m0 + wr*64 + i*16 + c4*4;
    #pragma unroll
    for (int j=0;j<4;j++) {
      int col = n0 + wc*64 + j*16 + li;
      float bv = bias[col];
      #pragma unroll
      for (int r=0;r<4;r++)
        outF[(size_t)(rbase+r)*1024 + col] = acc[i][j][r] + bv;
    }
  }
}

// ------- causal flash attention: block-staged K/V + cvt_pk/max3 VALU diet ---
__global__ __launch_bounds__(256, 2) void attn_kern(
    const ushort* __restrict__ Qb, const ushort* __restrict__ Kb,
    const ushort* __restrict__ Vt, ushort* __restrict__ Ob)
{
  __shared__ __align__(16) ushort Ks[2][32*68];   // [s][d] stride 68
  __shared__ __align__(16) ushort Vs[2][64*44];   // [dv][s32] stride 44
  __shared__ __align__(16) ushort Pb[4][32*40];   // per-wave P [q][kv]
  __shared__ __align__(16) ushort OT[4][32*72];   // per-wave epilogue transpose
  const int t = threadIdx.x, l = t & 63, w = t >> 6;
  const int bid = blockIdx.x;
  const int x = bid & 7, i0 = bid >> 3;
  const int bh = x*16 + (i0 >> 2);                // bh clustered per XCD
  const int g  = i0 & 3;
  const int p  = g*4 + w;
  const int qta = p, qtb = 31 - p;
  const int NT = 32 - g*4;                        // block-uniform tile count

  const int col = l & 31, hi = l >> 5;
  const ushort* Qp = Qb + (size_t)bh*65536;
  const ushort* Kp = Kb + (size_t)bh*65536;
  const ushort* Vp = Vt + (size_t)bh*65536;

  const int ks_row = t >> 3, ks_c = t & 7;
  const int vs_row = t >> 2, vs_c = t & 3;

  short8 qfa[4], qfb[4];
  #pragma unroll
  for (int m=0;m<4;m++) {
    qfa[m] = *(const short8*)&Qp[(size_t)(qta*32+col)*64 + m*16 + hi*8];
    qfb[m] = *(const short8*)&Qp[(size_t)(qtb*32+col)*64 + m*16 + hi*8];
  }

  f32x16 aA0 = (f32x16)0.0f, aA1 = (f32x16)0.0f;
  f32x16 aB0 = (f32x16)0.0f, aB1 = (f32x16)0.0f;
  float mA = -1e30f, lA = 0.0f, mB = -1e30f, lB = 0.0f;
  ushort* Pw = &Pb[w][0];

  auto PROC = [&](f32x16& s, bool diag, float& mR, float& lS,
                  f32x16& o0, f32x16& o1, const short8* vf0, const short8* vf1) {
    if (diag) {
      #pragma unroll
      for (int r=0;r<16;r++) {
        int kvl = (r&3) + ((r>>2)<<3) + 4*hi;
        s[r] = (kvl > col) ? -1e9f : s[r];
      }
    }
    // max via v_max3 fusion: 16 elems -> 5 max3 + 2 max3 + 1 max
    float t0 = fmaxf(fmaxf(s[0], s[1]), s[2]);
    float t1 = fmaxf(fmaxf(s[3], s[4]), s[5]);
    float t2 = fmaxf(fmaxf(s[6], s[7]), s[8]);
    float t3 = fmaxf(fmaxf(s[9], s[10]), s[11]);
    float t4 = fmaxf(fmaxf(s[12], s[13]), s[14]);
    float mx = fmaxf(fmaxf(fmaxf(t0, t1), t2), fmaxf(fmaxf(t3, t4), s[15]));
    mx = fmaxf(mx, __shfl_xor(mx, 32));
    if (__any(mx - mR > 8.0f)) {          // T13 defer-max (log2 units)
      float mN = fmaxf(mR, mx);
      float corr = __builtin_amdgcn_exp2f(mR - mN);
      mR = mN; lS *= corr;
      #pragma unroll
      for (int r=0;r<16;r++) { o0[r] *= corr; o1[r] *= corr; }
    }
    float pr[16];
    #pragma unroll
    for (int r=0;r<16;r++) pr[r] = __builtin_amdgcn_exp2f(s[r] - mR);
    float s8[8];
    #pragma unroll
    for (int r2=0;r2<8;r2++) s8[r2] = pr[2*r2] + pr[2*r2+1];
    #pragma unroll
    for (int r2=0;r2<4;r2++) s8[r2] += s8[r2+4];
    float rs = (s8[0]+s8[1]) + (s8[2]+s8[3]);
    rs += __shfl_xor(rs, 32);
    lS += rs;
    #pragma unroll
    for (int r2=0;r2<8;r2++) {
      int r = 2*r2;
      int kv = (r&3) + ((r>>2)<<3) + 4*hi;
      *(unsigned*)&Pw[col*40 + kv] = cvtpk(pr[r], pr[r+1]);
    }
    short8 pb0 = *(const short8*)&Pw[col*40 + hi*8];
    short8 pb1 = *(const short8*)&Pw[col*40 + 16 + hi*8];
    o0 = __builtin_amdgcn_mfma_f32_32x32x16_bf16(vf0[0], pb0, o0, 0,0,0);
    o0 = __builtin_amdgcn_mfma_f32_32x32x16_bf16(vf0[1], pb1, o0, 0,0,0);
    o1 = __builtin_amdgcn_mfma_f32_32x32x16_bf16(vf1[0], pb0, o1, 0,0,0);
    o1 = __builtin_amdgcn_mfma_f32_32x32x16_bf16(vf1[1], pb1, o1, 0,0,0);
  };

  { // stage tile 0 into buf 0
    uint4 k0v = *(const uint4*)&Kp[(size_t)ks_row*64 + ks_c*8];
    uint4 v0v = *(const uint4*)&Vp[(size_t)vs_row*1024 + vs_c*8];
    *(uint4*)&Ks[0][ks_row*68 + ks_c*8] = k0v;
    *(uint4*)&Vs[0][vs_row*44 + vs_c*8] = v0v;
  }
  __syncthreads();

  for (int kt = 0; kt < NT; ++kt) {
    const int cur = kt & 1;
    const bool pre = (kt + 1 < NT);
    uint4 kn2, vn2;
    if (pre) {   // T14: global prefetch of tile kt+1 (overlaps PROC below)
      kn2 = *(const uint4*)&Kp[(size_t)((kt+1)*32+ks_row)*64 + ks_c*8];
      vn2 = *(const uint4*)&Vp[(size_t)vs_row*1024 + (kt+1)*32 + vs_c*8];
    }

    short8 kf[4], vf0[2], vf1[2];
    #pragma unroll
    for (int m=0;m<4;m++)
      kf[m] = *(const short8*)&Ks[cur][col*68 + m*16 + hi*8];
    #pragma unroll
    for (int m=0;m<2;m++) {
      vf0[m] = *(const short8*)&Vs[cur][col*44 + m*16 + hi*8];
      vf1[m] = *(const short8*)&Vs[cur][(col+32)*44 + m*16 + hi*8];
    }

    const bool doB = (kt <= qtb), doA = (kt <= qta);
    if (doB) {
      f32x16 sB = (f32x16)0.0f;
      #pragma unroll
      for (int m=0;m<4;m++)
        sB = __builtin_amdgcn_mfma_f32_32x32x16_bf16(kf[m], qfb[m], sB, 0, 0, 0);
      if (doA) {
        f32x16 sA = (f32x16)0.0f;
        #pragma unroll
        for (int m=0;m<4;m++)
          sA = __builtin_amdgcn_mfma_f32_32x32x16_bf16(kf[m], qfa[m], sA, 0, 0, 0);
        PROC(sB, kt == qtb, mB, lB, aB0, aB1, vf0, vf1);
        PROC(sA, kt == qta, mA, lA, aA0, aA1, vf0, vf1);
      } else {
        PROC(sB, kt == qtb, mB, lB, aB0, aB1, vf0, vf1);
      }
    }

    if (pre) {
      *(uint4*)&Ks[cur^1][ks_row*68 + ks_c*8] = kn2;
      *(uint4*)&Vs[cur^1][vs_row*44 + vs_c*8] = vn2;
    }
    __syncthreads();
  }

  // epilogue: O[dv][q] regs -> LDS transpose -> coalesced global store
  const int b = bh >> 4, h = bh & 15;
  auto EPI = [&](int qt, float lS, const f32x16& o0, const f32x16& o1) {
    float inv = 1.0f / lS;
    ushort* o = &OT[w][0];
    #pragma unroll
    for (int r2=0;r2<8;r2++) {
      int r = 2*r2;
      int dv = (r&3) + ((r>>2)<<3) + 4*hi;
      *(unsigned*)&o[col*72 + dv]      = cvtpk(o0[r]*inv, o0[r+1]*inv);
      *(unsigned*)&o[col*72 + 32 + dv] = cvtpk(o1[r]*inv, o1[r+1]*inv);
    }
    #pragma unroll
    for (int it=0; it<4; ++it) {
      int q = it*8 + (l>>3), c8 = (l&7)*8;
      uint4 v = *(const uint4*)&o[q*72 + c8];
      int qg = qt*32 + q;
      *(uint4*)&Ob[(size_t)(b*1024+qg)*1024 + h*64 + c8] = v;
    }
  };
  EPI(qta, lA, aA0, aA1);
  EPI(qtb, lB, aB0, aB1);
}

extern "C" void kernel_launch(void* const* d_in, const int* in_sizes, int n_in,
                              void* d_out, int out_size, void* d_ws, size_t ws_size,
                              hipStream_t stream) {
  const float* query = (const float*)d_in[0];
  const float* Wq = (const float*)d_in[4];
  const float* bq = (const float*)d_in[5];
  const float* Wk = (const float*)d_in[6];
  const float* bk = (const float*)d_in[7];
  const float* Wv = (const float*)d_in[8];
  const float* bv = (const float*)d_in[9];
  const float* Wo = (const float*)d_in[10];
  const float* bo = (const float*)d_in[11];

  char* wsb = (char*)d_ws;
  ushort* Xb   = (ushort*)(wsb);                  // 16 MB
  ushort* Wqkv = (ushort*)(wsb + 16777216);       // 6 MB
  float*  Bqkv = (float*) (wsb + 23068672);       // 12 KB
  ushort* Wob  = (ushort*)(wsb + 23080960);       // 2 MB
  ushort* Qb   = (ushort*)(wsb + 25178112);       // 16 MB
  ushort* Kb   = (ushort*)(wsb + 41955328);       // 16 MB
  ushort* Vtb  = (ushort*)(wsb + 58732544);       // 16 MB  [bh][d][s]
  ushort* Ob   = (ushort*)(wsb + 75509760);       // 16 MB

  hipLaunchKernelGGL(pack_all_kern, dim3(5120), dim3(256), 0, stream,
                     query, Xb, Wq, Wk, Wv, bq, bk, bv, Wo, Wqkv, Bqkv, Wob);
  hipLaunchKernelGGL(gemmw_kern, dim3(768), dim3(256), 0, stream,
                     Xb, Wqkv, Bqkv, Qb, Kb, Vtb);
  hipLaunchKernelGGL(attn_kern, dim3(512), dim3(256), 0, stream, Qb, Kb, Vtb, Ob);
  hipLaunchKernelGGL(gemm128_kern<1>, dim3(512), dim3(256), 0, stream,
                     Ob, Wob, bo, (ushort*)nullptr, (ushort*)nullptr, (ushort*)nullptr,
                     (float*)d_out);
}